// Round 6
// baseline (296.840 us; speedup 1.0000x reference)
//
#include <hip/hip_runtime.h>
#include <math.h>

#define SEQ 4096
#define DIM 1024

typedef __bf16 bf16;
typedef __bf16 bf16x8 __attribute__((ext_vector_type(8)));
typedef __bf16 bf16x4 __attribute__((ext_vector_type(4)));
typedef float f32x4 __attribute__((ext_vector_type(4)));

#define GLOAD_LDS16(g, l)                                              \
    __builtin_amdgcn_global_load_lds(                                  \
        (const __attribute__((address_space(1))) void*)(g),            \
        (__attribute__((address_space(3))) void*)(l), 16, 0, 0)

// ---------------------------------------------------------------------------
// Split f32 -> (hi, lo) bf16, vectorized by 4.
// ---------------------------------------------------------------------------
__global__ __launch_bounds__(256) void split_f32(const float* __restrict__ in,
                                                 bf16* __restrict__ hi,
                                                 bf16* __restrict__ lo, int n4) {
    const int i = blockIdx.x * 256 + threadIdx.x;
    if (i >= n4) return;
    const float4 v = ((const float4*)in)[i];
    const float vv[4] = {v.x, v.y, v.z, v.w};
    bf16x4 h, l;
#pragma unroll
    for (int q = 0; q < 4; ++q) {
        const bf16 hq = (bf16)vv[q];
        h[q] = hq;
        l[q] = (bf16)(vv[q] - (float)hq);
    }
    ((bf16x4*)hi)[i] = h;
    ((bf16x4*)lo)[i] = l;
}

// ---------------------------------------------------------------------------
// Transpose-convert W [DIM][DIM] f32 -> W^T bf16 (hi, and lo if SPLIT).
// ---------------------------------------------------------------------------
template <bool SPLIT>
__global__ __launch_bounds__(256) void wtrans(const float* __restrict__ W,
                                              bf16* __restrict__ hiT,
                                              bf16* __restrict__ loT) {
    __shared__ float tile[32][33];
    const int tid = threadIdx.x;
    const int r0 = blockIdx.x * 32;  // W row (k)
    const int c0 = blockIdx.y * 32;  // W col (n)
    {
        const int r = tid >> 3, c = (tid & 7) * 4;
        const float4 v = *(const float4*)&W[(size_t)(r0 + r) * DIM + c0 + c];
        tile[r][c + 0] = v.x;
        tile[r][c + 1] = v.y;
        tile[r][c + 2] = v.z;
        tile[r][c + 3] = v.w;
    }
    __syncthreads();
    {
        const int n = tid >> 3;
        const int k = (tid & 7) * 4;
        bf16x4 h, l;
#pragma unroll
        for (int q = 0; q < 4; ++q) {
            const float x = tile[k + q][n];
            const bf16 hq = (bf16)x;
            h[q] = hq;
            if (SPLIT) l[q] = (bf16)(x - (float)hq);
        }
        *(bf16x4*)&hiT[(size_t)(c0 + n) * DIM + r0 + k] = h;
        if (SPLIT) *(bf16x4*)&loT[(size_t)(c0 + n) * DIM + r0 + k] = l;
    }
}

// ---------------------------------------------------------------------------
// Unified 128x128 MFMA GEMM (proven round-5): BK=64, 256 thr, double-buffered
// counted-vmcnt, XOR swizzle, XCD swizzle.  Used for projections and PV.
// ---------------------------------------------------------------------------
#define EPI_F32 0
#define EPI_SPLIT 1
#define EPI_TRANS 2

template <int EPI, int NPAIR, int KTILES>
__global__ __launch_bounds__(256, 2) void gemm128p(
    const bf16* __restrict__ A0, const bf16* __restrict__ A1,
    const bf16* __restrict__ A2,
    const bf16* __restrict__ B0a, const bf16* __restrict__ B1a,
    const bf16* __restrict__ B2a,
    const bf16* __restrict__ B0b, const bf16* __restrict__ B1b,
    const bf16* __restrict__ B2b,
    int ysplit, int N, float scale,
    void* out0a, void* out1a, void* out0b, void* out1b) {
    constexpr int K = KTILES * 64;
    __shared__ __align__(16) bf16 As[2][128 * 64];
    __shared__ __align__(16) bf16 Bs[2][128 * 64];

    const int tid = threadIdx.x;
    const int lane = tid & 63;
    const int wid = tid >> 6;
    const int wr = wid >> 1, wc = wid & 1;

    const int total = (int)(gridDim.y << 5);
    int lid = (int)blockIdx.y * 32 + (int)blockIdx.x;
    lid = (lid & 7) * (total >> 3) + (lid >> 3);
    const int bx = lid & 31;
    int by = lid >> 5;

    const bf16 *B0, *B1, *B2;
    void *o0, *o1;
    if (by >= ysplit) {
        by -= ysplit;
        B0 = B0b; B1 = B1b; B2 = B2b;
        o0 = out0b; o1 = out1b;
    } else {
        B0 = B0a; B1 = B1a; B2 = B2a;
        o0 = out0a; o1 = out1a;
    }
    const int m0 = bx * 128;
    const int n0 = by * 128;

    const bf16* APs[3] = {A0, A1, A2};
    const bf16* BPs[3] = {B0, B1, B2};
    const int nt = NPAIR * KTILES;

    f32x4 acc[4][4];
#pragma unroll
    for (int i = 0; i < 4; ++i)
#pragma unroll
        for (int j = 0; j < 4; ++j) acc[i][j] = (f32x4){0.f, 0.f, 0.f, 0.f};

    auto STAGE = [&](int t, int b) {
        const int pass = t / KTILES;
        const int k0 = (t % KTILES) * 64;
        const bf16* Ap = APs[pass];
        const bf16* Bp = BPs[pass];
#pragma unroll
        for (int L = 0; L < 4; ++L) {
            const int idx = L * 256 + tid;
            const int row = idx >> 3;
            const int sc = ((idx & 7) * 16) ^ ((row & 7) << 4);
            const int ldsu = (L * 256 + (tid & ~63)) * 8;
            GLOAD_LDS16(Ap + (size_t)(m0 + row) * K + k0 + (sc >> 1),
                        &As[b][ldsu]);
            GLOAD_LDS16(Bp + (size_t)(n0 + row) * K + k0 + (sc >> 1),
                        &Bs[b][ldsu]);
        }
    };

    STAGE(0, 0);

    for (int t = 0; t < nt; ++t) {
        const int cur = t & 1;
        __builtin_amdgcn_s_barrier();
        asm volatile("" ::: "memory");
        if (t + 1 < nt) {
            STAGE(t + 1, cur ^ 1);
            asm volatile("s_waitcnt vmcnt(8)" ::: "memory");
        } else {
            asm volatile("s_waitcnt vmcnt(0)" ::: "memory");
        }
        __builtin_amdgcn_s_barrier();
        asm volatile("" ::: "memory");

#pragma unroll
        for (int kk = 0; kk < 2; ++kk) {
            const int cb = kk * 64 + (lane >> 4) * 16;
            bf16x8 af[4], bv[4];
#pragma unroll
            for (int i = 0; i < 4; ++i) {
                const int r = wr * 64 + i * 16 + (lane & 15);
                af[i] = *(const bf16x8*)(&As[cur][r * 64 +
                                                  ((cb ^ ((r & 7) << 4)) >> 1)]);
            }
#pragma unroll
            for (int j = 0; j < 4; ++j) {
                const int r = wc * 64 + j * 16 + (lane & 15);
                bv[j] = *(const bf16x8*)(&Bs[cur][r * 64 +
                                                  ((cb ^ ((r & 7) << 4)) >> 1)]);
            }
            __builtin_amdgcn_s_setprio(1);
#pragma unroll
            for (int i = 0; i < 4; ++i)
#pragma unroll
                for (int j = 0; j < 4; ++j)
                    acc[i][j] = __builtin_amdgcn_mfma_f32_16x16x32_bf16(
                        af[i], bv[j], acc[i][j], 0, 0, 0);
            __builtin_amdgcn_s_setprio(0);
        }
    }

    const int row0 = m0 + wr * 64 + (lane >> 4) * 4;
    const int col0 = n0 + wc * 64 + (lane & 15);

    if (EPI == EPI_F32) {
        float* O = (float*)o0;
#pragma unroll
        for (int i = 0; i < 4; ++i)
#pragma unroll
            for (int j = 0; j < 4; ++j)
#pragma unroll
                for (int q = 0; q < 4; ++q)
                    O[(size_t)(row0 + i * 16 + q) * N + col0 + j * 16] =
                        acc[i][j][q] * scale;
    } else if (EPI == EPI_SPLIT) {
        bf16* Hi = (bf16*)o0;
        bf16* Lo = (bf16*)o1;
#pragma unroll
        for (int i = 0; i < 4; ++i)
#pragma unroll
            for (int j = 0; j < 4; ++j)
#pragma unroll
                for (int q = 0; q < 4; ++q) {
                    const float x = acc[i][j][q];
                    const bf16 h = (bf16)x;
                    const size_t idx = (size_t)(row0 + i * 16 + q) * N + col0 + j * 16;
                    Hi[idx] = h;
                    Lo[idx] = (bf16)(x - (float)h);
                }
    } else {
        bf16* OT = (bf16*)o0;
#pragma unroll
        for (int i = 0; i < 4; ++i)
#pragma unroll
            for (int j = 0; j < 4; ++j) {
                bf16x4 v;
#pragma unroll
                for (int q = 0; q < 4; ++q) v[q] = (bf16)acc[i][j][q];
                *(bf16x4*)&OT[(size_t)(col0 + j * 16) * SEQ + row0 + i * 16] = v;
            }
    }
}

// ---------------------------------------------------------------------------
// QK^T 256x256 GEMM, lead-2 "read-all-then-overwrite" schedule.
// 512 thr (8 waves, 2M x 4N; wave tile 128x64), BK=64, 2 LDS buffer sets
// (128 KB). Per iter t (buf c = t&1):
//   ds_read ALL A-frags (af[8][2]) + B kk0 frags; lgkmcnt(0); barrier
//     -> A-region of buf c is dead for this tile
//   stage tile t+2's A INTO buf c's A-region; ds_read B kk1; MFMA kk0+kk1
//   barrier -> B-region dead; stage tile t+2's B; vmcnt(8) (tile t+1 landed,
//   only tile t+2's 8 loads may remain in flight); barrier
// Prefetch lead ~= 1 full iteration -> covers HBM latency; no mid-loop drain.
// C = sum_p A_p [M][K] @ B_p^T [N][K], f32 out, scaled.
// ---------------------------------------------------------------------------
template <int NPAIR, int KTILES>
__global__ __launch_bounds__(512, 1) void qk256(
    const bf16* __restrict__ A0, const bf16* __restrict__ B0,
    const bf16* __restrict__ A1, const bf16* __restrict__ B1,
    const bf16* __restrict__ A2, const bf16* __restrict__ B2,
    int N, float scale, float* __restrict__ out) {
    constexpr int K = KTILES * 64;
    constexpr int nt = NPAIR * KTILES;
    __shared__ __align__(16) bf16 As[2][256 * 64];   // 64 KB
    __shared__ __align__(16) bf16 Bs[2][256 * 64];   // 64 KB

    const int tid = threadIdx.x;
    const int lane = tid & 63;
    const int wid = tid >> 6;
    const int wr = wid >> 2;   // 0..1: M half (128 rows)
    const int wc = wid & 3;    // 0..3: N quarter (64 cols)

    // XCD swizzle: 256 blocks -> 16x16 tile grid, 256 % 8 == 0.
    const int lid = ((int)blockIdx.x & 7) * 32 + ((int)blockIdx.x >> 3);
    const int m0 = (lid >> 4) * 256;
    const int n0 = (lid & 15) * 256;

    const bf16* APs[3] = {A0, A1, A2};
    const bf16* BPs[3] = {B0, B1, B2};

    f32x4 acc[8][4];
#pragma unroll
    for (int i = 0; i < 8; ++i)
#pragma unroll
        for (int j = 0; j < 4; ++j) acc[i][j] = (f32x4){0.f, 0.f, 0.f, 0.f};

    // Stage one operand's 256x64 tile (4 x gload_lds16 per thread).
    // Linear LDS dest + XOR-pre-swizzled global source (involution with
    // the swizzled fragment read) — same formulas as proven gemm256.
    auto STAGE_A = [&](int t, int b) {
        const bf16* Ap = APs[t / KTILES];
        const int k0 = (t % KTILES) * 64;
#pragma unroll
        for (int L = 0; L < 4; ++L) {
            const int idx = L * 512 + tid;
            const int row = idx >> 3;
            const int sc = ((idx & 7) * 16) ^ ((row & 7) << 4);
            const int ldsu = (L * 512 + (tid & ~63)) * 8;
            GLOAD_LDS16(Ap + (size_t)(m0 + row) * K + k0 + (sc >> 1),
                        &As[b][ldsu]);
        }
    };
    auto STAGE_B = [&](int t, int b) {
        const bf16* Bp = BPs[t / KTILES];
        const int k0 = (t % KTILES) * 64;
#pragma unroll
        for (int L = 0; L < 4; ++L) {
            const int idx = L * 512 + tid;
            const int row = idx >> 3;
            const int sc = ((idx & 7) * 16) ^ ((row & 7) << 4);
            const int ldsu = (L * 512 + (tid & ~63)) * 8;
            GLOAD_LDS16(Bp + (size_t)(n0 + row) * K + k0 + (sc >> 1),
                        &Bs[b][ldsu]);
        }
    };

    // Prologue: tiles 0 and 1 in flight; wait for tile 0 (oldest 8 loads).
    STAGE_A(0, 0);
    STAGE_B(0, 0);
    STAGE_A(1, 1);
    STAGE_B(1, 1);
    asm volatile("s_waitcnt vmcnt(8)" ::: "memory");
    __builtin_amdgcn_s_barrier();
    asm volatile("" ::: "memory");

    for (int t = 0; t < nt; ++t) {
        const int cur = t & 1;

        // --- Phase 1: read ALL A fragments + B kk0 fragments ---
        bf16x8 af[8][2], bv0[4], bv1[4];
#pragma unroll
        for (int i = 0; i < 8; ++i) {
            const int r = wr * 128 + i * 16 + (lane & 15);
            const int rx = (r & 7) << 4;
#pragma unroll
            for (int kk = 0; kk < 2; ++kk) {
                const int cb = kk * 64 + (lane >> 4) * 16;
                af[i][kk] = *(const bf16x8*)(&As[cur][r * 64 + ((cb ^ rx) >> 1)]);
            }
        }
#pragma unroll
        for (int j = 0; j < 4; ++j) {
            const int r = wc * 64 + j * 16 + (lane & 15);
            const int cb = (lane >> 4) * 16;               // kk = 0
            bv0[j] = *(const bf16x8*)(&Bs[cur][r * 64 +
                                               ((cb ^ ((r & 7) << 4)) >> 1)]);
        }
        asm volatile("s_waitcnt lgkmcnt(0)" ::: "memory");  // my reads retired
        __builtin_amdgcn_s_barrier();                       // everyone's too
        asm volatile("" ::: "memory");

        // --- Phase 2: A-region of buf cur is free -> stage tile t+2's A ---
        if (t + 2 < nt) STAGE_A(t + 2, cur);

        // B kk1 fragments (B-region untouched until the next barrier).
#pragma unroll
        for (int j = 0; j < 4; ++j) {
            const int r = wc * 64 + j * 16 + (lane & 15);
            const int cb = 64 + (lane >> 4) * 16;           // kk = 1
            bv1[j] = *(const bf16x8*)(&Bs[cur][r * 64 +
                                               ((cb ^ ((r & 7) << 4)) >> 1)]);
        }

        __builtin_amdgcn_s_setprio(1);
#pragma unroll
        for (int i = 0; i < 8; ++i)
#pragma unroll
            for (int j = 0; j < 4; ++j)
                acc[i][j] = __builtin_amdgcn_mfma_f32_16x16x32_bf16(
                    af[i][0], bv0[j], acc[i][j], 0, 0, 0);
#pragma unroll
        for (int i = 0; i < 8; ++i)
#pragma unroll
            for (int j = 0; j < 4; ++j)
                acc[i][j] = __builtin_amdgcn_mfma_f32_16x16x32_bf16(
                    af[i][1], bv1[j], acc[i][j], 0, 0, 0);
        __builtin_amdgcn_s_setprio(0);

        // --- Phase 3: B-region free -> stage tile t+2's B; fence t+1 ---
        asm volatile("s_waitcnt lgkmcnt(0)" ::: "memory");
        __builtin_amdgcn_s_barrier();
        asm volatile("" ::: "memory");
        if (t + 2 < nt) {
            STAGE_B(t + 2, cur);
            // newest 8 = tile t+2's A+B; everything older (tile t+1) landed
            asm volatile("s_waitcnt vmcnt(8)" ::: "memory");
        } else {
            asm volatile("s_waitcnt vmcnt(0)" ::: "memory");
        }
        __builtin_amdgcn_s_barrier();
        asm volatile("" ::: "memory");
    }

    // Epilogue (same C/D mapping as proven gemm256).
    const int row0 = m0 + wr * 128 + (lane >> 4) * 4;
    const int col0 = n0 + wc * 64 + (lane & 15);
#pragma unroll
    for (int i = 0; i < 8; ++i)
#pragma unroll
        for (int j = 0; j < 4; ++j)
#pragma unroll
            for (int q = 0; q < 4; ++q)
                out[(size_t)(row0 + i * 16 + q) * N + col0 + j * 16] =
                    acc[i][j][q] * scale;
}

// ---------------------------------------------------------------------------
// Row softmax: S (f32 [SEQ][SEQ], already scaled) -> P (bf16, normalized).
// ---------------------------------------------------------------------------
__global__ __launch_bounds__(256) void softmax_rows(const float* __restrict__ S,
                                                    bf16* __restrict__ P) {
    __shared__ float red[8];
    const int tid = threadIdx.x;
    const size_t row = blockIdx.x;
    const float4* s4 = (const float4*)(S + row * SEQ);

    float4 v[4];
    float mx = -1e30f;
#pragma unroll
    for (int c = 0; c < 4; ++c) {
        v[c] = s4[c * 256 + tid];
        mx = fmaxf(mx, fmaxf(fmaxf(v[c].x, v[c].y), fmaxf(v[c].z, v[c].w)));
    }
#pragma unroll
    for (int m = 32; m >= 1; m >>= 1) mx = fmaxf(mx, __shfl_xor(mx, m));
    if ((tid & 63) == 0) red[tid >> 6] = mx;
    __syncthreads();
    mx = fmaxf(fmaxf(red[0], red[1]), fmaxf(red[2], red[3]));

    float e[16];
    float sum = 0.f;
#pragma unroll
    for (int c = 0; c < 4; ++c) {
        e[c * 4 + 0] = __expf(v[c].x - mx);
        e[c * 4 + 1] = __expf(v[c].y - mx);
        e[c * 4 + 2] = __expf(v[c].z - mx);
        e[c * 4 + 3] = __expf(v[c].w - mx);
        sum += e[c * 4] + e[c * 4 + 1] + e[c * 4 + 2] + e[c * 4 + 3];
    }
#pragma unroll
    for (int m = 32; m >= 1; m >>= 1) sum += __shfl_xor(sum, m);
    if ((tid & 63) == 0) red[4 + (tid >> 6)] = sum;
    __syncthreads();
    sum = red[4] + red[5] + red[6] + red[7];
    const float inv = 1.f / sum;

    bf16* prow = P + row * SEQ;
#pragma unroll
    for (int c = 0; c < 4; ++c) {
        bf16x4 o;
#pragma unroll
        for (int q = 0; q < 4; ++q) o[q] = (bf16)(e[c * 4 + q] * inv);
        ((bf16x4*)prow)[c * 256 + tid] = o;
    }
}

// ---------------------------------------------------------------------------
extern "C" void kernel_launch(void* const* d_in, const int* in_sizes, int n_in,
                              void* d_out, int out_size, void* d_ws, size_t ws_size,
                              hipStream_t stream) {
    const float* x  = (const float*)d_in[0];
    const float* wq = (const float*)d_in[1];
    const float* wk = (const float*)d_in[2];
    const float* wv = (const float*)d_in[3];
    float* O = (float*)d_out;

    char* ws = (char*)d_ws;
    const size_t MB = 1024 * 1024;
    bf16* Qhi = (bf16*)(ws + 0 * MB);
    bf16* Qlo = (bf16*)(ws + 8 * MB);
    bf16* Khi = (bf16*)(ws + 16 * MB);
    bf16* Klo = (bf16*)(ws + 24 * MB);
    bf16* VT  = (bf16*)(ws + 32 * MB);
    float* S  = (float*)(ws + 40 * MB);   // 64 MB
    bf16* P   = (bf16*)(ws + 0 * MB);     // overlays dead Q/K
    bf16* Xhi   = (bf16*)(ws + 40 * MB);  // converts die before S written
    bf16* Xlo   = (bf16*)(ws + 48 * MB);
    bf16* WqhiT = (bf16*)(ws + 56 * MB);
    bf16* WqloT = (bf16*)(ws + 58 * MB);
    bf16* WkhiT = (bf16*)(ws + 60 * MB);
    bf16* WkloT = (bf16*)(ws + 62 * MB);
    bf16* WvT   = (bf16*)(ws + 64 * MB);

    split_f32<<<(SEQ * DIM / 4 + 255) / 256, 256, 0, stream>>>(x, Xhi, Xlo,
                                                               SEQ * DIM / 4);
    const dim3 wgrid(DIM / 32, DIM / 32);
    wtrans<true><<<wgrid, 256, 0, stream>>>(wq, WqhiT, WqloT);
    wtrans<true><<<wgrid, 256, 0, stream>>>(wk, WkhiT, WkloT);
    wtrans<false><<<wgrid, 256, 0, stream>>>(wv, WvT, nullptr);

    // Q and K projections merged in one dispatch (by<8 -> Q, by>=8 -> K).
    gemm128p<EPI_SPLIT, 3, 16><<<dim3(32, 16), 256, 0, stream>>>(
        Xhi, Xhi, Xlo,
        WqhiT, WqloT, WqhiT,
        WkhiT, WkloT, WkhiT,
        8, DIM, 1.f, Qhi, Qlo, Khi, Klo);

    // V projection (transposed bf16 store).
    gemm128p<EPI_TRANS, 1, 16><<<dim3(32, 8), 256, 0, stream>>>(
        Xhi, Xhi, Xhi,
        WvT, WvT, WvT,
        WvT, WvT, WvT,
        8, DIM, 1.f, VT, nullptr, VT, nullptr);

    // QK^T: 3-way split (hi.hi + hi.lo + lo.hi), scaled, f32 out.
    qk256<3, 16><<<256, 512, 0, stream>>>(
        Qhi, Khi, Qhi, Klo, Qlo, Khi, SEQ, 0.03125f, S);

    softmax_rows<<<SEQ, 256, 0, stream>>>(S, P);

    // O = P @ V  (B^T = VT), K = SEQ.
    gemm128p<EPI_F32, 1, 64><<<dim3(32, 8), 256, 0, stream>>>(
        P, P, P,
        VT, VT, VT,
        VT, VT, VT,
        8, DIM, 1.f, O, nullptr, O, nullptr);
}

// Round 7
// 271.045 us; speedup vs baseline: 1.0952x; 1.0952x over previous
//
#include <hip/hip_runtime.h>
#include <math.h>

#define SEQ 4096
#define DIM 1024

typedef __bf16 bf16;
typedef __bf16 bf16x8 __attribute__((ext_vector_type(8)));
typedef __bf16 bf16x4 __attribute__((ext_vector_type(4)));
typedef float f32x4 __attribute__((ext_vector_type(4)));

#define GLOAD_LDS16(g, l)                                              \
    __builtin_amdgcn_global_load_lds(                                  \
        (const __attribute__((address_space(1))) void*)(g),            \
        (__attribute__((address_space(3))) void*)(l), 16, 0, 0)

// ---------------------------------------------------------------------------
// Split f32 -> (hi, lo) bf16, vectorized by 4.
// ---------------------------------------------------------------------------
__global__ __launch_bounds__(256) void split_f32(const float* __restrict__ in,
                                                 bf16* __restrict__ hi,
                                                 bf16* __restrict__ lo, int n4) {
    const int i = blockIdx.x * 256 + threadIdx.x;
    if (i >= n4) return;
    const float4 v = ((const float4*)in)[i];
    const float vv[4] = {v.x, v.y, v.z, v.w};
    bf16x4 h, l;
#pragma unroll
    for (int q = 0; q < 4; ++q) {
        const bf16 hq = (bf16)vv[q];
        h[q] = hq;
        l[q] = (bf16)(vv[q] - (float)hq);
    }
    ((bf16x4*)hi)[i] = h;
    ((bf16x4*)lo)[i] = l;
}

// ---------------------------------------------------------------------------
// Merged transpose-convert of all three W [DIM][DIM] f32 -> W^T bf16.
// z = 0: wq (split hi/lo), z = 1: wk (split), z = 2: wv (hi only).
// ---------------------------------------------------------------------------
__global__ __launch_bounds__(256) void wtrans3(
    const float* __restrict__ Wq, const float* __restrict__ Wk,
    const float* __restrict__ Wv,
    bf16* __restrict__ QhiT, bf16* __restrict__ QloT,
    bf16* __restrict__ KhiT, bf16* __restrict__ KloT,
    bf16* __restrict__ VhiT) {
    __shared__ float tile[32][33];
    const int tid = threadIdx.x;
    const int r0 = blockIdx.x * 32;  // W row (k)
    const int c0 = blockIdx.y * 32;  // W col (n)
    const int z = blockIdx.z;
    const float* W = (z == 0) ? Wq : (z == 1) ? Wk : Wv;
    bf16* hiT = (z == 0) ? QhiT : (z == 1) ? KhiT : VhiT;
    bf16* loT = (z == 0) ? QloT : (z == 1) ? KloT : nullptr;
    const bool split = (z < 2);
    {
        const int r = tid >> 3, c = (tid & 7) * 4;
        const float4 v = *(const float4*)&W[(size_t)(r0 + r) * DIM + c0 + c];
        tile[r][c + 0] = v.x;
        tile[r][c + 1] = v.y;
        tile[r][c + 2] = v.z;
        tile[r][c + 3] = v.w;
    }
    __syncthreads();
    {
        const int n = tid >> 3;
        const int k = (tid & 7) * 4;
        bf16x4 h, l;
#pragma unroll
        for (int q = 0; q < 4; ++q) {
            const float x = tile[k + q][n];
            const bf16 hq = (bf16)x;
            h[q] = hq;
            l[q] = (bf16)(x - (float)hq);
        }
        *(bf16x4*)&hiT[(size_t)(c0 + n) * DIM + r0 + k] = h;
        if (split) *(bf16x4*)&loT[(size_t)(c0 + n) * DIM + r0 + k] = l;
    }
}

// ---------------------------------------------------------------------------
// Unified 128x128 MFMA GEMM (proven round-5): BK=64, 256 thr, double-buffered
// counted-vmcnt, XOR swizzle, XCD swizzle.  Used for projections and PV.
// ---------------------------------------------------------------------------
#define EPI_F32 0
#define EPI_SPLIT 1
#define EPI_TRANS 2

template <int EPI, int NPAIR, int KTILES>
__global__ __launch_bounds__(256, 2) void gemm128p(
    const bf16* __restrict__ A0, const bf16* __restrict__ A1,
    const bf16* __restrict__ A2,
    const bf16* __restrict__ B0a, const bf16* __restrict__ B1a,
    const bf16* __restrict__ B2a,
    const bf16* __restrict__ B0b, const bf16* __restrict__ B1b,
    const bf16* __restrict__ B2b,
    int ysplit, int N, float scale,
    void* out0a, void* out1a, void* out0b, void* out1b) {
    constexpr int K = KTILES * 64;
    __shared__ __align__(16) bf16 As[2][128 * 64];
    __shared__ __align__(16) bf16 Bs[2][128 * 64];

    const int tid = threadIdx.x;
    const int lane = tid & 63;
    const int wid = tid >> 6;
    const int wr = wid >> 1, wc = wid & 1;

    const int total = (int)(gridDim.y << 5);
    int lid = (int)blockIdx.y * 32 + (int)blockIdx.x;
    lid = (lid & 7) * (total >> 3) + (lid >> 3);
    const int bx = lid & 31;
    int by = lid >> 5;

    const bf16 *B0, *B1, *B2;
    void *o0, *o1;
    if (by >= ysplit) {
        by -= ysplit;
        B0 = B0b; B1 = B1b; B2 = B2b;
        o0 = out0b; o1 = out1b;
    } else {
        B0 = B0a; B1 = B1a; B2 = B2a;
        o0 = out0a; o1 = out1a;
    }
    const int m0 = bx * 128;
    const int n0 = by * 128;

    const bf16* APs[3] = {A0, A1, A2};
    const bf16* BPs[3] = {B0, B1, B2};
    const int nt = NPAIR * KTILES;

    f32x4 acc[4][4];
#pragma unroll
    for (int i = 0; i < 4; ++i)
#pragma unroll
        for (int j = 0; j < 4; ++j) acc[i][j] = (f32x4){0.f, 0.f, 0.f, 0.f};

    auto STAGE = [&](int t, int b) {
        const int pass = t / KTILES;
        const int k0 = (t % KTILES) * 64;
        const bf16* Ap = APs[pass];
        const bf16* Bp = BPs[pass];
#pragma unroll
        for (int L = 0; L < 4; ++L) {
            const int idx = L * 256 + tid;
            const int row = idx >> 3;
            const int sc = ((idx & 7) * 16) ^ ((row & 7) << 4);
            const int ldsu = (L * 256 + (tid & ~63)) * 8;
            GLOAD_LDS16(Ap + (size_t)(m0 + row) * K + k0 + (sc >> 1),
                        &As[b][ldsu]);
            GLOAD_LDS16(Bp + (size_t)(n0 + row) * K + k0 + (sc >> 1),
                        &Bs[b][ldsu]);
        }
    };

    STAGE(0, 0);

    for (int t = 0; t < nt; ++t) {
        const int cur = t & 1;
        __builtin_amdgcn_s_barrier();
        asm volatile("" ::: "memory");
        if (t + 1 < nt) {
            STAGE(t + 1, cur ^ 1);
            asm volatile("s_waitcnt vmcnt(8)" ::: "memory");
        } else {
            asm volatile("s_waitcnt vmcnt(0)" ::: "memory");
        }
        __builtin_amdgcn_s_barrier();
        asm volatile("" ::: "memory");

#pragma unroll
        for (int kk = 0; kk < 2; ++kk) {
            const int cb = kk * 64 + (lane >> 4) * 16;
            bf16x8 af[4], bv[4];
#pragma unroll
            for (int i = 0; i < 4; ++i) {
                const int r = wr * 64 + i * 16 + (lane & 15);
                af[i] = *(const bf16x8*)(&As[cur][r * 64 +
                                                  ((cb ^ ((r & 7) << 4)) >> 1)]);
            }
#pragma unroll
            for (int j = 0; j < 4; ++j) {
                const int r = wc * 64 + j * 16 + (lane & 15);
                bv[j] = *(const bf16x8*)(&Bs[cur][r * 64 +
                                                  ((cb ^ ((r & 7) << 4)) >> 1)]);
            }
            __builtin_amdgcn_s_setprio(1);
#pragma unroll
            for (int i = 0; i < 4; ++i)
#pragma unroll
                for (int j = 0; j < 4; ++j)
                    acc[i][j] = __builtin_amdgcn_mfma_f32_16x16x32_bf16(
                        af[i], bv[j], acc[i][j], 0, 0, 0);
            __builtin_amdgcn_s_setprio(0);
        }
    }

    const int row0 = m0 + wr * 64 + (lane >> 4) * 4;
    const int col0 = n0 + wc * 64 + (lane & 15);

    if (EPI == EPI_F32) {
        float* O = (float*)o0;
#pragma unroll
        for (int i = 0; i < 4; ++i)
#pragma unroll
            for (int j = 0; j < 4; ++j)
#pragma unroll
                for (int q = 0; q < 4; ++q)
                    O[(size_t)(row0 + i * 16 + q) * N + col0 + j * 16] =
                        acc[i][j][q] * scale;
    } else if (EPI == EPI_SPLIT) {
        bf16* Hi = (bf16*)o0;
        bf16* Lo = (bf16*)o1;
#pragma unroll
        for (int i = 0; i < 4; ++i)
#pragma unroll
            for (int j = 0; j < 4; ++j)
#pragma unroll
                for (int q = 0; q < 4; ++q) {
                    const float x = acc[i][j][q];
                    const bf16 h = (bf16)x;
                    const size_t idx = (size_t)(row0 + i * 16 + q) * N + col0 + j * 16;
                    Hi[idx] = h;
                    Lo[idx] = (bf16)(x - (float)h);
                }
    } else {
        bf16* OT = (bf16*)o0;
#pragma unroll
        for (int i = 0; i < 4; ++i)
#pragma unroll
            for (int j = 0; j < 4; ++j) {
                bf16x4 v;
#pragma unroll
                for (int q = 0; q < 4; ++q) v[q] = (bf16)acc[i][j][q];
                *(bf16x4*)&OT[(size_t)(col0 + j * 16) * SEQ + row0 + i * 16] = v;
            }
    }
}

// ---------------------------------------------------------------------------
// 256x256 MFMA GEMM for QK^T (round-4 proven, 917 TF): 512 thr (8 waves 2x4),
// BK=64, double-buffered LDS, counted-vmcnt prefetch (never vmcnt(0) in
// loop), XOR-swizzled LDS, XCD-aware block swizzle.
// C = sum_p A_p @ B_p^T, f32 out, scaled.
// ---------------------------------------------------------------------------
template <int NPAIR>
__global__ __launch_bounds__(512, 2) void gemm256(
    const bf16* __restrict__ A0, const bf16* __restrict__ B0,
    const bf16* __restrict__ A1, const bf16* __restrict__ B1,
    const bf16* __restrict__ A2, const bf16* __restrict__ B2,
    int N, int K, float scale, float* __restrict__ out) {
    __shared__ __align__(16) bf16 As[2][256 * 64];   // 64 KB
    __shared__ __align__(16) bf16 Bs[2][256 * 64];   // 64 KB

    const int tid = threadIdx.x;
    const int lane = tid & 63;
    const int wid = tid >> 6;       // 0..7
    const int wr = wid >> 2;        // 0..1 (M half)
    const int wc = wid & 3;         // 0..3 (N quarter)

    // XCD swizzle: grid is 256 blocks (16x16), 256 % 8 == 0 -> simple remap.
    const int wg = (blockIdx.x & 7) * 32 + (blockIdx.x >> 3);
    const int m0 = (wg >> 4) * 256;
    const int n0 = (wg & 15) * 256;

    const bf16* APs[3] = {A0, A1, A2};
    const bf16* BPs[3] = {B0, B1, B2};
    const int ktiles = K / 64;
    const int nt = NPAIR * ktiles;

    f32x4 acc[8][4];
#pragma unroll
    for (int i = 0; i < 8; ++i)
#pragma unroll
        for (int j = 0; j < 4; ++j) acc[i][j] = (f32x4){0.f, 0.f, 0.f, 0.f};

    auto STAGE = [&](int t, int b) {
        const bf16* Ap = APs[t >> 4];   // ktiles == 16
        const bf16* Bp = BPs[t >> 4];
        const int k0 = (t & 15) * 64;
#pragma unroll
        for (int L = 0; L < 4; ++L) {
            const int idx = L * 512 + tid;          // 16B slot index
            const int row = idx >> 3;               // 0..255
            const int sc = ((idx & 7) * 16) ^ ((row & 7) << 4);  // src col-byte
            const int ldsu = (L * 512 + (tid & ~63)) * 8;        // uniform elems
            GLOAD_LDS16(Ap + (size_t)(m0 + row) * K + k0 + (sc >> 1),
                        &As[b][ldsu]);
            GLOAD_LDS16(Bp + (size_t)(n0 + row) * K + k0 + (sc >> 1),
                        &Bs[b][ldsu]);
        }
    };

    STAGE(0, 0);

    for (int t = 0; t < nt; ++t) {
        const int cur = t & 1;
        // Barrier A: all waves finished reading buf cur^1 (iter t-1 body).
        __builtin_amdgcn_s_barrier();
        asm volatile("" ::: "memory");
        if (t + 1 < nt) {
            STAGE(t + 1, cur ^ 1);
            asm volatile("s_waitcnt vmcnt(8)" ::: "memory");  // STAGE(t) done
        } else {
            asm volatile("s_waitcnt vmcnt(0)" ::: "memory");
        }
        // Barrier B: everyone's STAGE(t) writes visible.
        __builtin_amdgcn_s_barrier();
        asm volatile("" ::: "memory");

#pragma unroll
        for (int kk = 0; kk < 2; ++kk) {
            const int cb = kk * 64 + (lane >> 4) * 16;  // col-byte of fragment
            bf16x8 af[8], bv[4];
#pragma unroll
            for (int i = 0; i < 8; ++i) {
                const int r = wr * 128 + i * 16 + (lane & 15);
                af[i] = *(const bf16x8*)(&As[cur][r * 64 +
                                                  ((cb ^ ((r & 7) << 4)) >> 1)]);
            }
#pragma unroll
            for (int j = 0; j < 4; ++j) {
                const int r = wc * 64 + j * 16 + (lane & 15);
                bv[j] = *(const bf16x8*)(&Bs[cur][r * 64 +
                                                  ((cb ^ ((r & 7) << 4)) >> 1)]);
            }
            __builtin_amdgcn_s_setprio(1);
#pragma unroll
            for (int i = 0; i < 8; ++i)
#pragma unroll
                for (int j = 0; j < 4; ++j)
                    acc[i][j] = __builtin_amdgcn_mfma_f32_16x16x32_bf16(
                        af[i], bv[j], acc[i][j], 0, 0, 0);
            __builtin_amdgcn_s_setprio(0);
        }
    }

    // Epilogue: C[m][n] f32, scaled.
    const int row0 = m0 + wr * 128 + (lane >> 4) * 4;
    const int col0 = n0 + wc * 64 + (lane & 15);
#pragma unroll
    for (int i = 0; i < 8; ++i)
#pragma unroll
        for (int j = 0; j < 4; ++j)
#pragma unroll
            for (int q = 0; q < 4; ++q)
                out[(size_t)(row0 + i * 16 + q) * N + col0 + j * 16] =
                    acc[i][j][q] * scale;
}

// ---------------------------------------------------------------------------
// Row softmax: S (f32 [SEQ][SEQ], already scaled) -> P (bf16, normalized).
// ---------------------------------------------------------------------------
__global__ __launch_bounds__(256) void softmax_rows(const float* __restrict__ S,
                                                    bf16* __restrict__ P) {
    __shared__ float red[8];
    const int tid = threadIdx.x;
    const size_t row = blockIdx.x;
    const float4* s4 = (const float4*)(S + row * SEQ);

    float4 v[4];
    float mx = -1e30f;
#pragma unroll
    for (int c = 0; c < 4; ++c) {
        v[c] = s4[c * 256 + tid];
        mx = fmaxf(mx, fmaxf(fmaxf(v[c].x, v[c].y), fmaxf(v[c].z, v[c].w)));
    }
#pragma unroll
    for (int m = 32; m >= 1; m >>= 1) mx = fmaxf(mx, __shfl_xor(mx, m));
    if ((tid & 63) == 0) red[tid >> 6] = mx;
    __syncthreads();
    mx = fmaxf(fmaxf(red[0], red[1]), fmaxf(red[2], red[3]));

    float e[16];
    float sum = 0.f;
#pragma unroll
    for (int c = 0; c < 4; ++c) {
        e[c * 4 + 0] = __expf(v[c].x - mx);
        e[c * 4 + 1] = __expf(v[c].y - mx);
        e[c * 4 + 2] = __expf(v[c].z - mx);
        e[c * 4 + 3] = __expf(v[c].w - mx);
        sum += e[c * 4] + e[c * 4 + 1] + e[c * 4 + 2] + e[c * 4 + 3];
    }
#pragma unroll
    for (int m = 32; m >= 1; m >>= 1) sum += __shfl_xor(sum, m);
    if ((tid & 63) == 0) red[4 + (tid >> 6)] = sum;
    __syncthreads();
    sum = red[4] + red[5] + red[6] + red[7];
    const float inv = 1.f / sum;

    bf16* prow = P + row * SEQ;
#pragma unroll
    for (int c = 0; c < 4; ++c) {
        bf16x4 o;
#pragma unroll
        for (int q = 0; q < 4; ++q) o[q] = (bf16)(e[c * 4 + q] * inv);
        ((bf16x4*)prow)[c * 256 + tid] = o;
    }
}

// ---------------------------------------------------------------------------
extern "C" void kernel_launch(void* const* d_in, const int* in_sizes, int n_in,
                              void* d_out, int out_size, void* d_ws, size_t ws_size,
                              hipStream_t stream) {
    const float* x  = (const float*)d_in[0];
    const float* wq = (const float*)d_in[1];
    const float* wk = (const float*)d_in[2];
    const float* wv = (const float*)d_in[3];
    float* O = (float*)d_out;

    char* ws = (char*)d_ws;
    const size_t MB = 1024 * 1024;
    bf16* Qhi = (bf16*)(ws + 0 * MB);
    bf16* Qlo = (bf16*)(ws + 8 * MB);
    bf16* Khi = (bf16*)(ws + 16 * MB);
    bf16* Klo = (bf16*)(ws + 24 * MB);
    bf16* VT  = (bf16*)(ws + 32 * MB);
    float* S  = (float*)(ws + 40 * MB);   // 64 MB
    bf16* P   = (bf16*)(ws + 0 * MB);     // overlays dead Q/K
    bf16* Xhi   = (bf16*)(ws + 40 * MB);  // converts die before S written
    bf16* Xlo   = (bf16*)(ws + 48 * MB);
    bf16* WqhiT = (bf16*)(ws + 56 * MB);
    bf16* WqloT = (bf16*)(ws + 58 * MB);
    bf16* WkhiT = (bf16*)(ws + 60 * MB);
    bf16* WkloT = (bf16*)(ws + 62 * MB);
    bf16* WvT   = (bf16*)(ws + 64 * MB);

    split_f32<<<(SEQ * DIM / 4 + 255) / 256, 256, 0, stream>>>(x, Xhi, Xlo,
                                                               SEQ * DIM / 4);
    // All three weight transposes in one dispatch.
    wtrans3<<<dim3(DIM / 32, DIM / 32, 3), 256, 0, stream>>>(
        wq, wk, wv, WqhiT, WqloT, WkhiT, WkloT, WvT);

    // Q and K projections merged in one dispatch (by<8 -> Q, by>=8 -> K).
    gemm128p<EPI_SPLIT, 3, 16><<<dim3(32, 16), 256, 0, stream>>>(
        Xhi, Xhi, Xlo,
        WqhiT, WqloT, WqhiT,
        WkhiT, WkloT, WkhiT,
        8, DIM, 1.f, Qhi, Qlo, Khi, Klo);

    // V projection (transposed bf16 store).
    gemm128p<EPI_TRANS, 1, 16><<<dim3(32, 8), 256, 0, stream>>>(
        Xhi, Xhi, Xhi,
        WvT, WvT, WvT,
        WvT, WvT, WvT,
        8, DIM, 1.f, VT, nullptr, VT, nullptr);

    // QK^T: 3-way split (hi.hi + hi.lo + lo.hi), scaled, f32 out.
    gemm256<3><<<256, 512, 0, stream>>>(
        Qhi, Khi, Qhi, Klo, Qlo, Khi, SEQ, DIM, 0.03125f, S);

    softmax_rows<<<SEQ, 256, 0, stream>>>(S, P);

    // O = P @ V  (B^T = VT), K = SEQ.
    gemm128p<EPI_F32, 1, 64><<<dim3(32, 8), 256, 0, stream>>>(
        P, P, P,
        VT, VT, VT,
        VT, VT, VT,
        8, DIM, 1.f, O, nullptr, O, nullptr);
}

// Round 8
// 270.273 us; speedup vs baseline: 1.0983x; 1.0029x over previous
//
#include <hip/hip_runtime.h>
#include <math.h>

#define SEQ 4096
#define DIM 1024

typedef __bf16 bf16;
typedef __bf16 bf16x8 __attribute__((ext_vector_type(8)));
typedef __bf16 bf16x4 __attribute__((ext_vector_type(4)));
typedef float f32x4 __attribute__((ext_vector_type(4)));

#define GLOAD_LDS16(g, l)                                              \
    __builtin_amdgcn_global_load_lds(                                  \
        (const __attribute__((address_space(1))) void*)(g),            \
        (__attribute__((address_space(3))) void*)(l), 16, 0, 0)

// ---------------------------------------------------------------------------
// Split f32 -> (hi, lo) bf16, vectorized by 4.
// ---------------------------------------------------------------------------
__global__ __launch_bounds__(256) void split_f32(const float* __restrict__ in,
                                                 bf16* __restrict__ hi,
                                                 bf16* __restrict__ lo, int n4) {
    const int i = blockIdx.x * 256 + threadIdx.x;
    if (i >= n4) return;
    const float4 v = ((const float4*)in)[i];
    const float vv[4] = {v.x, v.y, v.z, v.w};
    bf16x4 h, l;
#pragma unroll
    for (int q = 0; q < 4; ++q) {
        const bf16 hq = (bf16)vv[q];
        h[q] = hq;
        l[q] = (bf16)(vv[q] - (float)hq);
    }
    ((bf16x4*)hi)[i] = h;
    ((bf16x4*)lo)[i] = l;
}

// ---------------------------------------------------------------------------
// Merged transpose-convert of all three W [DIM][DIM] f32 -> W^T bf16.
// z = 0: wq (split hi/lo), z = 1: wk (split), z = 2: wv (hi only).
// ---------------------------------------------------------------------------
__global__ __launch_bounds__(256) void wtrans3(
    const float* __restrict__ Wq, const float* __restrict__ Wk,
    const float* __restrict__ Wv,
    bf16* __restrict__ QhiT, bf16* __restrict__ QloT,
    bf16* __restrict__ KhiT, bf16* __restrict__ KloT,
    bf16* __restrict__ VhiT) {
    __shared__ float tile[32][33];
    const int tid = threadIdx.x;
    const int r0 = blockIdx.x * 32;  // W row (k)
    const int c0 = blockIdx.y * 32;  // W col (n)
    const int z = blockIdx.z;
    const float* W = (z == 0) ? Wq : (z == 1) ? Wk : Wv;
    bf16* hiT = (z == 0) ? QhiT : (z == 1) ? KhiT : VhiT;
    bf16* loT = (z == 0) ? QloT : (z == 1) ? KloT : nullptr;
    const bool split = (z < 2);
    {
        const int r = tid >> 3, c = (tid & 7) * 4;
        const float4 v = *(const float4*)&W[(size_t)(r0 + r) * DIM + c0 + c];
        tile[r][c + 0] = v.x;
        tile[r][c + 1] = v.y;
        tile[r][c + 2] = v.z;
        tile[r][c + 3] = v.w;
    }
    __syncthreads();
    {
        const int n = tid >> 3;
        const int k = (tid & 7) * 4;
        bf16x4 h, l;
#pragma unroll
        for (int q = 0; q < 4; ++q) {
            const float x = tile[k + q][n];
            const bf16 hq = (bf16)x;
            h[q] = hq;
            l[q] = (bf16)(x - (float)hq);
        }
        *(bf16x4*)&hiT[(size_t)(c0 + n) * DIM + r0 + k] = h;
        if (split) *(bf16x4*)&loT[(size_t)(c0 + n) * DIM + r0 + k] = l;
    }
}

// ---------------------------------------------------------------------------
// Unified 128x128 MFMA GEMM (proven round-5): BK=64, 256 thr, double-buffered
// counted-vmcnt, XOR swizzle, XCD swizzle.  Used for projections and PV.
// ---------------------------------------------------------------------------
#define EPI_F32 0
#define EPI_SPLIT 1
#define EPI_TRANS 2

template <int EPI, int NPAIR, int KTILES>
__global__ __launch_bounds__(256, 2) void gemm128p(
    const bf16* __restrict__ A0, const bf16* __restrict__ A1,
    const bf16* __restrict__ A2,
    const bf16* __restrict__ B0a, const bf16* __restrict__ B1a,
    const bf16* __restrict__ B2a,
    const bf16* __restrict__ B0b, const bf16* __restrict__ B1b,
    const bf16* __restrict__ B2b,
    int ysplit, int N, float scale,
    void* out0a, void* out1a, void* out0b, void* out1b) {
    constexpr int K = KTILES * 64;
    __shared__ __align__(16) bf16 As[2][128 * 64];
    __shared__ __align__(16) bf16 Bs[2][128 * 64];

    const int tid = threadIdx.x;
    const int lane = tid & 63;
    const int wid = tid >> 6;
    const int wr = wid >> 1, wc = wid & 1;

    const int total = (int)(gridDim.y << 5);
    int lid = (int)blockIdx.y * 32 + (int)blockIdx.x;
    lid = (lid & 7) * (total >> 3) + (lid >> 3);
    const int bx = lid & 31;
    int by = lid >> 5;

    const bf16 *B0, *B1, *B2;
    void *o0, *o1;
    if (by >= ysplit) {
        by -= ysplit;
        B0 = B0b; B1 = B1b; B2 = B2b;
        o0 = out0b; o1 = out1b;
    } else {
        B0 = B0a; B1 = B1a; B2 = B2a;
        o0 = out0a; o1 = out1a;
    }
    const int m0 = bx * 128;
    const int n0 = by * 128;

    const bf16* APs[3] = {A0, A1, A2};
    const bf16* BPs[3] = {B0, B1, B2};
    const int nt = NPAIR * KTILES;

    f32x4 acc[4][4];
#pragma unroll
    for (int i = 0; i < 4; ++i)
#pragma unroll
        for (int j = 0; j < 4; ++j) acc[i][j] = (f32x4){0.f, 0.f, 0.f, 0.f};

    auto STAGE = [&](int t, int b) {
        const int pass = t / KTILES;
        const int k0 = (t % KTILES) * 64;
        const bf16* Ap = APs[pass];
        const bf16* Bp = BPs[pass];
#pragma unroll
        for (int L = 0; L < 4; ++L) {
            const int idx = L * 256 + tid;
            const int row = idx >> 3;
            const int sc = ((idx & 7) * 16) ^ ((row & 7) << 4);
            const int ldsu = (L * 256 + (tid & ~63)) * 8;
            GLOAD_LDS16(Ap + (size_t)(m0 + row) * K + k0 + (sc >> 1),
                        &As[b][ldsu]);
            GLOAD_LDS16(Bp + (size_t)(n0 + row) * K + k0 + (sc >> 1),
                        &Bs[b][ldsu]);
        }
    };

    STAGE(0, 0);

    for (int t = 0; t < nt; ++t) {
        const int cur = t & 1;
        __builtin_amdgcn_s_barrier();
        asm volatile("" ::: "memory");
        if (t + 1 < nt) {
            STAGE(t + 1, cur ^ 1);
            asm volatile("s_waitcnt vmcnt(8)" ::: "memory");
        } else {
            asm volatile("s_waitcnt vmcnt(0)" ::: "memory");
        }
        __builtin_amdgcn_s_barrier();
        asm volatile("" ::: "memory");

#pragma unroll
        for (int kk = 0; kk < 2; ++kk) {
            const int cb = kk * 64 + (lane >> 4) * 16;
            bf16x8 af[4], bv[4];
#pragma unroll
            for (int i = 0; i < 4; ++i) {
                const int r = wr * 64 + i * 16 + (lane & 15);
                af[i] = *(const bf16x8*)(&As[cur][r * 64 +
                                                  ((cb ^ ((r & 7) << 4)) >> 1)]);
            }
#pragma unroll
            for (int j = 0; j < 4; ++j) {
                const int r = wc * 64 + j * 16 + (lane & 15);
                bv[j] = *(const bf16x8*)(&Bs[cur][r * 64 +
                                                  ((cb ^ ((r & 7) << 4)) >> 1)]);
            }
            __builtin_amdgcn_s_setprio(1);
#pragma unroll
            for (int i = 0; i < 4; ++i)
#pragma unroll
                for (int j = 0; j < 4; ++j)
                    acc[i][j] = __builtin_amdgcn_mfma_f32_16x16x32_bf16(
                        af[i], bv[j], acc[i][j], 0, 0, 0);
            __builtin_amdgcn_s_setprio(0);
        }
    }

    const int row0 = m0 + wr * 64 + (lane >> 4) * 4;
    const int col0 = n0 + wc * 64 + (lane & 15);

    if (EPI == EPI_F32) {
        float* O = (float*)o0;
#pragma unroll
        for (int i = 0; i < 4; ++i)
#pragma unroll
            for (int j = 0; j < 4; ++j)
#pragma unroll
                for (int q = 0; q < 4; ++q)
                    O[(size_t)(row0 + i * 16 + q) * N + col0 + j * 16] =
                        acc[i][j][q] * scale;
    } else if (EPI == EPI_SPLIT) {
        bf16* Hi = (bf16*)o0;
        bf16* Lo = (bf16*)o1;
#pragma unroll
        for (int i = 0; i < 4; ++i)
#pragma unroll
            for (int j = 0; j < 4; ++j)
#pragma unroll
                for (int q = 0; q < 4; ++q) {
                    const float x = acc[i][j][q];
                    const bf16 h = (bf16)x;
                    const size_t idx = (size_t)(row0 + i * 16 + q) * N + col0 + j * 16;
                    Hi[idx] = h;
                    Lo[idx] = (bf16)(x - (float)h);
                }
    } else {
        bf16* OT = (bf16*)o0;
#pragma unroll
        for (int i = 0; i < 4; ++i)
#pragma unroll
            for (int j = 0; j < 4; ++j) {
                bf16x4 v;
#pragma unroll
                for (int q = 0; q < 4; ++q) v[q] = (bf16)acc[i][j][q];
                *(bf16x4*)&OT[(size_t)(col0 + j * 16) * SEQ + row0 + i * 16] = v;
            }
    }
}

// ---------------------------------------------------------------------------
// QK^T 256x256 GEMM — 8-phase schedule (guide m201 template port).
// 512 thr (8 waves 2Mx4N, wave tile 128x64), BK=64, 2 dbuf (128 KB LDS).
// Per K-tile t (buf cur=t&1), 4 phases, each {ds_reads; 1 half-tile stage;
// barrier; setprio(1); 16 MFMA; setprio(0); barrier}:
//   P1: read A i0-3 (rows 0-63,128-191 = Ap1) + B j0-1 (strips = Bp1);
//       stage B(t+1)p2 -> other buf.        MFMA i0-3 x j0-1.
//   P2: read B j2-3 (Bp2); stage A(t+2)p1.  MFMA i0-3 x j2-3.
//   P3: read A i4-7 (Ap2); stage B(t+2)p1.  MFMA i4-7 x j0-1.
//   P4: stage A(t+2)p2; vmcnt(6) (= 3 half-tiles in flight -> tile t+1
//       fully landed); barrier.             MFMA i4-7 x j2-3.
// Every staged region is read-complete (all waves) before its stage issues:
// stage region X in phase p only if X's reads happened in phases < p (reads
// drain before that phase's MFMA; trailing barrier publishes).  vmcnt never
// drains to 0 mid-loop.  Same XOR-swizzle involution as proven gemm256.
// ---------------------------------------------------------------------------
template <int NPAIR>
__global__ __launch_bounds__(512, 1) void qk8p(
    const bf16* __restrict__ A0, const bf16* __restrict__ B0,
    const bf16* __restrict__ A1, const bf16* __restrict__ B1,
    const bf16* __restrict__ A2, const bf16* __restrict__ B2,
    int N, float scale, float* __restrict__ out) {
    constexpr int KT = 16;              // K-tiles per pass (K = 1024)
    constexpr int K = KT * 64;
    constexpr int nt = NPAIR * KT;
    __shared__ __align__(16) bf16 As[2][256 * 64];   // 64 KB
    __shared__ __align__(16) bf16 Bs[2][256 * 64];   // 64 KB

    const int tid = threadIdx.x;
    const int lane = tid & 63;
    const int wid = tid >> 6;
    const int wr = wid >> 2;   // 0..1: M half (128 rows)
    const int wc = wid & 3;    // 0..3: N quarter (64 rows of B)

    // XCD swizzle (256 blocks, 16x16 tiles).
    const int wg = ((int)blockIdx.x & 7) * 32 + ((int)blockIdx.x >> 3);
    const int m0 = (wg >> 4) * 256;
    const int n0 = (wg & 15) * 256;

    const bf16* APs[3] = {A0, A1, A2};
    const bf16* BPs[3] = {B0, B1, B2};

    // Stage geometry. Half-tile modes: 0 = A.part1 (rows 0-63,128-191),
    // 1 = A.part2 (rows 64-127,192-255), 2 = B.part1 (rows wc*64+0..31
    // strips), 3 = B.part2 (strips +32).  2 loads (L) per thread per stage.
    // Row mappings preserve row&7 -> swizzle involution unchanged; each
    // wave's 64 lanes cover 8 contiguous rows -> gload_lds dest is linear.
    int srcb[4][2];   // global elem offset (excl. k0), per-lane
    int ldsb[4][2];   // LDS elem base (wave-uniform)
#pragma unroll
    for (int m = 0; m < 4; ++m)
#pragma unroll
        for (int L = 0; L < 2; ++L) {
            const int idx = L * 512 + tid;
            const int rp = idx >> 3;           // 0..127
            const int slot = idx & 7;
            int row;
            if (m < 2) row = ((rp & 63) | ((rp & 64) << 1)) + (m == 1 ? 64 : 0);
            else       row = ((rp & 31) | ((rp & 96) << 1)) + (m == 3 ? 32 : 0);
            const int sc = (slot * 16) ^ ((row & 7) << 4);
            srcb[m][L] = ((m < 2 ? m0 : n0) + row) * K + (sc >> 1);
            const int rpu = (L * 512 + (tid & ~63)) >> 3;   // 8-aligned
            int rowu;
            if (m < 2) rowu = ((rpu & 63) | ((rpu & 64) << 1)) + (m == 1 ? 64 : 0);
            else       rowu = ((rpu & 31) | ((rpu & 96) << 1)) + (m == 3 ? 32 : 0);
            ldsb[m][L] = rowu * 64;
        }

#define STG(mm, P, LB, k0v)                                            \
    {                                                                  \
        GLOAD_LDS16((P) + srcb[mm][0] + (k0v), (LB) + ldsb[mm][0]);    \
        GLOAD_LDS16((P) + srcb[mm][1] + (k0v), (LB) + ldsb[mm][1]);    \
    }

    f32x4 acc[8][4];
#pragma unroll
    for (int i = 0; i < 8; ++i)
#pragma unroll
        for (int j = 0; j < 4; ++j) acc[i][j] = (f32x4){0.f, 0.f, 0.f, 0.f};

    // Prologue: 7 half-tiles (tile0 complete + tile1 minus B.p2).
    STG(0, APs[0], &As[0][0], 0);
    STG(1, APs[0], &As[0][0], 0);
    STG(2, BPs[0], &Bs[0][0], 0);
    STG(3, BPs[0], &Bs[0][0], 0);
    STG(0, APs[0], &As[1][0], 64);
    STG(1, APs[0], &As[1][0], 64);
    STG(2, BPs[0], &Bs[1][0], 64);
    asm volatile("s_waitcnt vmcnt(6)" ::: "memory");   // tile 0 landed
    __builtin_amdgcn_s_barrier();
    asm volatile("" ::: "memory");

    const int l15 = lane & 15;
    const int kq = (lane >> 4) * 16;   // fragment col-byte base

    bf16x8 af[4][2], bv[4][2];

    for (int t = 0; t < nt; ++t) {
        const int cur = t & 1;
        const int u1 = t + 1, u2 = t + 2;
        const int k1 = (u1 & (KT - 1)) * 64, k2 = (u2 & (KT - 1)) * 64;

        // ================= Phase 1 =================
#pragma unroll
        for (int i = 0; i < 4; ++i) {
            const int r = wr * 128 + i * 16 + l15;
            const int rx = (r & 7) << 4;
            af[i][0] = *(const bf16x8*)(&As[cur][r * 64 + ((kq ^ rx) >> 1)]);
            af[i][1] = *(const bf16x8*)(&As[cur][r * 64 + (((64 + kq) ^ rx) >> 1)]);
        }
#pragma unroll
        for (int j = 0; j < 2; ++j) {
            const int r = wc * 64 + j * 16 + l15;
            const int rx = (r & 7) << 4;
            bv[j][0] = *(const bf16x8*)(&Bs[cur][r * 64 + ((kq ^ rx) >> 1)]);
            bv[j][1] = *(const bf16x8*)(&Bs[cur][r * 64 + (((64 + kq) ^ rx) >> 1)]);
        }
        if (u1 < nt) STG(3, BPs[u1 >> 4], &Bs[cur ^ 1][0], k1);
        __builtin_amdgcn_s_barrier();
        asm volatile("" ::: "memory");
        __builtin_amdgcn_s_setprio(1);
#pragma unroll
        for (int kk = 0; kk < 2; ++kk)
#pragma unroll
            for (int i = 0; i < 4; ++i)
#pragma unroll
                for (int j = 0; j < 2; ++j)
                    acc[i][j] = __builtin_amdgcn_mfma_f32_16x16x32_bf16(
                        af[i][kk], bv[j][kk], acc[i][j], 0, 0, 0);
        __builtin_amdgcn_s_setprio(0);
        __builtin_amdgcn_s_barrier();
        asm volatile("" ::: "memory");

        // ================= Phase 2 =================
#pragma unroll
        for (int j = 2; j < 4; ++j) {
            const int r = wc * 64 + j * 16 + l15;
            const int rx = (r & 7) << 4;
            bv[j][0] = *(const bf16x8*)(&Bs[cur][r * 64 + ((kq ^ rx) >> 1)]);
            bv[j][1] = *(const bf16x8*)(&Bs[cur][r * 64 + (((64 + kq) ^ rx) >> 1)]);
        }
        if (u2 < nt) STG(0, APs[u2 >> 4], &As[cur][0], k2);
        __builtin_amdgcn_s_barrier();
        asm volatile("" ::: "memory");
        __builtin_amdgcn_s_setprio(1);
#pragma unroll
        for (int kk = 0; kk < 2; ++kk)
#pragma unroll
            for (int i = 0; i < 4; ++i)
#pragma unroll
                for (int j = 2; j < 4; ++j)
                    acc[i][j] = __builtin_amdgcn_mfma_f32_16x16x32_bf16(
                        af[i][kk], bv[j][kk], acc[i][j], 0, 0, 0);
        __builtin_amdgcn_s_setprio(0);
        __builtin_amdgcn_s_barrier();
        asm volatile("" ::: "memory");

        // ================= Phase 3 =================
#pragma unroll
        for (int i = 0; i < 4; ++i) {
            const int r = wr * 128 + (i + 4) * 16 + l15;
            const int rx = (r & 7) << 4;
            af[i][0] = *(const bf16x8*)(&As[cur][r * 64 + ((kq ^ rx) >> 1)]);
            af[i][1] = *(const bf16x8*)(&As[cur][r * 64 + (((64 + kq) ^ rx) >> 1)]);
        }
        if (u2 < nt) STG(2, BPs[u2 >> 4], &Bs[cur][0], k2);
        __builtin_amdgcn_s_barrier();
        asm volatile("" ::: "memory");
        __builtin_amdgcn_s_setprio(1);
#pragma unroll
        for (int kk = 0; kk < 2; ++kk)
#pragma unroll
            for (int i = 0; i < 4; ++i)
#pragma unroll
                for (int j = 0; j < 2; ++j)
                    acc[i + 4][j] = __builtin_amdgcn_mfma_f32_16x16x32_bf16(
                        af[i][kk], bv[j][kk], acc[i + 4][j], 0, 0, 0);
        __builtin_amdgcn_s_setprio(0);
        __builtin_amdgcn_s_barrier();
        asm volatile("" ::: "memory");

        // ================= Phase 4 =================
        if (u2 < nt) {
            STG(1, APs[u2 >> 4], &As[cur][0], k2);
            asm volatile("s_waitcnt vmcnt(6)" ::: "memory");
        } else {
            asm volatile("s_waitcnt vmcnt(0)" ::: "memory");
        }
        __builtin_amdgcn_s_barrier();
        asm volatile("" ::: "memory");
        __builtin_amdgcn_s_setprio(1);
#pragma unroll
        for (int kk = 0; kk < 2; ++kk)
#pragma unroll
            for (int i = 0; i < 4; ++i)
#pragma unroll
                for (int j = 2; j < 4; ++j)
                    acc[i + 4][j] = __builtin_amdgcn_mfma_f32_16x16x32_bf16(
                        af[i][kk], bv[j][kk], acc[i + 4][j], 0, 0, 0);
        __builtin_amdgcn_s_setprio(0);
        __builtin_amdgcn_s_barrier();
        asm volatile("" ::: "memory");
    }
#undef STG

    // Epilogue (same C/D mapping as proven gemm256).
    const int row0 = m0 + wr * 128 + (lane >> 4) * 4;
    const int col0 = n0 + wc * 64 + l15;
#pragma unroll
    for (int i = 0; i < 8; ++i)
#pragma unroll
        for (int j = 0; j < 4; ++j)
#pragma unroll
            for (int q = 0; q < 4; ++q)
                out[(size_t)(row0 + i * 16 + q) * N + col0 + j * 16] =
                    acc[i][j][q] * scale;
}

// ---------------------------------------------------------------------------
// Row softmax: S (f32 [SEQ][SEQ], already scaled) -> P (bf16, normalized).
// ---------------------------------------------------------------------------
__global__ __launch_bounds__(256) void softmax_rows(const float* __restrict__ S,
                                                    bf16* __restrict__ P) {
    __shared__ float red[8];
    const int tid = threadIdx.x;
    const size_t row = blockIdx.x;
    const float4* s4 = (const float4*)(S + row * SEQ);

    float4 v[4];
    float mx = -1e30f;
#pragma unroll
    for (int c = 0; c < 4; ++c) {
        v[c] = s4[c * 256 + tid];
        mx = fmaxf(mx, fmaxf(fmaxf(v[c].x, v[c].y), fmaxf(v[c].z, v[c].w)));
    }
#pragma unroll
    for (int m = 32; m >= 1; m >>= 1) mx = fmaxf(mx, __shfl_xor(mx, m));
    if ((tid & 63) == 0) red[tid >> 6] = mx;
    __syncthreads();
    mx = fmaxf(fmaxf(red[0], red[1]), fmaxf(red[2], red[3]));

    float e[16];
    float sum = 0.f;
#pragma unroll
    for (int c = 0; c < 4; ++c) {
        e[c * 4 + 0] = __expf(v[c].x - mx);
        e[c * 4 + 1] = __expf(v[c].y - mx);
        e[c * 4 + 2] = __expf(v[c].z - mx);
        e[c * 4 + 3] = __expf(v[c].w - mx);
        sum += e[c * 4] + e[c * 4 + 1] + e[c * 4 + 2] + e[c * 4 + 3];
    }
#pragma unroll
    for (int m = 32; m >= 1; m >>= 1) sum += __shfl_xor(sum, m);
    if ((tid & 63) == 0) red[4 + (tid >> 6)] = sum;
    __syncthreads();
    sum = red[4] + red[5] + red[6] + red[7];
    const float inv = 1.f / sum;

    bf16* prow = P + row * SEQ;
#pragma unroll
    for (int c = 0; c < 4; ++c) {
        bf16x4 o;
#pragma unroll
        for (int q = 0; q < 4; ++q) o[q] = (bf16)(e[c * 4 + q] * inv);
        ((bf16x4*)prow)[c * 256 + tid] = o;
    }
}

// ---------------------------------------------------------------------------
extern "C" void kernel_launch(void* const* d_in, const int* in_sizes, int n_in,
                              void* d_out, int out_size, void* d_ws, size_t ws_size,
                              hipStream_t stream) {
    const float* x  = (const float*)d_in[0];
    const float* wq = (const float*)d_in[1];
    const float* wk = (const float*)d_in[2];
    const float* wv = (const float*)d_in[3];
    float* O = (float*)d_out;

    char* ws = (char*)d_ws;
    const size_t MB = 1024 * 1024;
    bf16* Qhi = (bf16*)(ws + 0 * MB);
    bf16* Qlo = (bf16*)(ws + 8 * MB);
    bf16* Khi = (bf16*)(ws + 16 * MB);
    bf16* Klo = (bf16*)(ws + 24 * MB);
    bf16* VT  = (bf16*)(ws + 32 * MB);
    float* S  = (float*)(ws + 40 * MB);   // 64 MB
    bf16* P   = (bf16*)(ws + 0 * MB);     // overlays dead Q/K
    bf16* Xhi   = (bf16*)(ws + 40 * MB);  // converts die before S written
    bf16* Xlo   = (bf16*)(ws + 48 * MB);
    bf16* WqhiT = (bf16*)(ws + 56 * MB);
    bf16* WqloT = (bf16*)(ws + 58 * MB);
    bf16* WkhiT = (bf16*)(ws + 60 * MB);
    bf16* WkloT = (bf16*)(ws + 62 * MB);
    bf16* WvT   = (bf16*)(ws + 64 * MB);

    split_f32<<<(SEQ * DIM / 4 + 255) / 256, 256, 0, stream>>>(x, Xhi, Xlo,
                                                               SEQ * DIM / 4);
    wtrans3<<<dim3(DIM / 32, DIM / 32, 3), 256, 0, stream>>>(
        wq, wk, wv, WqhiT, WqloT, WkhiT, WkloT, WvT);

    // Q and K projections merged in one dispatch (by<8 -> Q, by>=8 -> K).
    gemm128p<EPI_SPLIT, 3, 16><<<dim3(32, 16), 256, 0, stream>>>(
        Xhi, Xhi, Xlo,
        WqhiT, WqloT, WqhiT,
        WkhiT, WkloT, WkhiT,
        8, DIM, 1.f, Qhi, Qlo, Khi, Klo);

    // V projection (transposed bf16 store).
    gemm128p<EPI_TRANS, 1, 16><<<dim3(32, 8), 256, 0, stream>>>(
        Xhi, Xhi, Xhi,
        WvT, WvT, WvT,
        WvT, WvT, WvT,
        8, DIM, 1.f, VT, nullptr, VT, nullptr);

    // QK^T: 3-way split (hi.hi + hi.lo + lo.hi), 8-phase schedule.
    qk8p<3><<<256, 512, 0, stream>>>(
        Qhi, Khi, Qhi, Klo, Qlo, Khi, SEQ, 0.03125f, S);

    softmax_rows<<<SEQ, 256, 0, stream>>>(S, P);

    // O = P @ V  (B^T = VT), K = SEQ.
    gemm128p<EPI_F32, 1, 64><<<dim3(32, 8), 256, 0, stream>>>(
        P, P, P,
        VT, VT, VT,
        VT, VT, VT,
        8, DIM, 1.f, O, nullptr, O, nullptr);
}

// Round 9
// 236.926 us; speedup vs baseline: 1.2529x; 1.1407x over previous
//
#include <hip/hip_runtime.h>
#include <math.h>

#define SEQ 4096
#define DIM 1024

typedef _Float16 f16;
typedef _Float16 f16x8 __attribute__((ext_vector_type(8)));
typedef _Float16 f16x4 __attribute__((ext_vector_type(4)));
typedef float f32x4 __attribute__((ext_vector_type(4)));

#define GLOAD_LDS16(g, l)                                              \
    __builtin_amdgcn_global_load_lds(                                  \
        (const __attribute__((address_space(1))) void*)(g),            \
        (__attribute__((address_space(3))) void*)(l), 16, 0, 0)

// ---------------------------------------------------------------------------
// Split f32 -> (hi, lo) fp16, vectorized by 4.
// ---------------------------------------------------------------------------
__global__ __launch_bounds__(256) void split16(const float* __restrict__ in,
                                               f16* __restrict__ hi,
                                               f16* __restrict__ lo, int n4) {
    const int i = blockIdx.x * 256 + threadIdx.x;
    if (i >= n4) return;
    const float4 v = ((const float4*)in)[i];
    const float vv[4] = {v.x, v.y, v.z, v.w};
    f16x4 h, l;
#pragma unroll
    for (int q = 0; q < 4; ++q) {
        const f16 hq = (f16)vv[q];
        h[q] = hq;
        l[q] = (f16)(vv[q] - (float)hq);
    }
    ((f16x4*)hi)[i] = h;
    ((f16x4*)lo)[i] = l;
}

// ---------------------------------------------------------------------------
// Transpose-convert weights -> W^T fp16.  z=0: wq-0.5, z=1: wk-0.5, z=2: wv.
// ---------------------------------------------------------------------------
__global__ __launch_bounds__(256) void wtrans3h(
    const float* __restrict__ Wq, const float* __restrict__ Wk,
    const float* __restrict__ Wv,
    f16* __restrict__ QT, f16* __restrict__ KT, f16* __restrict__ VT) {
    __shared__ float tile[32][33];
    const int tid = threadIdx.x;
    const int r0 = blockIdx.x * 32;  // W row (k)
    const int c0 = blockIdx.y * 32;  // W col (n)
    const int z = blockIdx.z;
    const float* W = (z == 0) ? Wq : (z == 1) ? Wk : Wv;
    f16* T = (z == 0) ? QT : (z == 1) ? KT : VT;
    const float off = (z < 2) ? 0.5f : 0.0f;
    {
        const int r = tid >> 3, c = (tid & 7) * 4;
        const float4 v = *(const float4*)&W[(size_t)(r0 + r) * DIM + c0 + c];
        tile[r][c + 0] = v.x;
        tile[r][c + 1] = v.y;
        tile[r][c + 2] = v.z;
        tile[r][c + 3] = v.w;
    }
    __syncthreads();
    {
        const int n = tid >> 3;
        const int k = (tid & 7) * 4;
        f16x4 h;
#pragma unroll
        for (int q = 0; q < 4; ++q) h[q] = (f16)(tile[k + q][n] - off);
        *(f16x4*)&T[(size_t)(c0 + n) * DIM + r0 + k] = h;
    }
}

// ---------------------------------------------------------------------------
// sx[m] = rowsum of X (f32).  One wave per row, grid 1024 x 4 waves.
// ---------------------------------------------------------------------------
__global__ __launch_bounds__(256) void rowsum_x(const float* __restrict__ X,
                                                float* __restrict__ sx) {
    const int row = blockIdx.x * 4 + (threadIdx.x >> 6);
    const int lane = threadIdx.x & 63;
    const float4* r4 = (const float4*)(X + (size_t)row * DIM);
    float s = 0.f;
#pragma unroll
    for (int c = 0; c < 4; ++c) {
        const float4 f = r4[lane + 64 * c];
        s += f.x + f.y + f.z + f.w;
    }
#pragma unroll
    for (int m = 32; m >= 1; m >>= 1) s += __shfl_xor(s, m);
    if (lane == 0) sx[row] = s;
}

// ---------------------------------------------------------------------------
// rq[m] = rowsum(Qh+Ql); rk[m] = rowsum(Kh+Kl).  y=0 -> Q, y=1 -> K.
// ---------------------------------------------------------------------------
__global__ __launch_bounds__(256) void rowsum_hl(
    const f16* __restrict__ Qh, const f16* __restrict__ Ql,
    const f16* __restrict__ Kh, const f16* __restrict__ Kl,
    float* __restrict__ rq, float* __restrict__ rk) {
    const f16 *H, *L;
    float* out;
    if (blockIdx.y == 0) { H = Qh; L = Ql; out = rq; }
    else                 { H = Kh; L = Kl; out = rk; }
    const int row = blockIdx.x * 4 + (threadIdx.x >> 6);
    const int lane = threadIdx.x & 63;
    const f16x8* h8 = (const f16x8*)(H + (size_t)row * DIM);
    const f16x8* l8 = (const f16x8*)(L + (size_t)row * DIM);
    float s = 0.f;
#pragma unroll
    for (int c = 0; c < 2; ++c) {
        const f16x8 a = h8[lane + 64 * c];
        const f16x8 b = l8[lane + 64 * c];
#pragma unroll
        for (int e = 0; e < 8; ++e) s += (float)a[e] + (float)b[e];
    }
#pragma unroll
    for (int m = 32; m >= 1; m >>= 1) s += __shfl_xor(s, m);
    if (lane == 0) out[row] = s;
}

// ---------------------------------------------------------------------------
// 128x128 fp16 MFMA GEMM (round-5 proven schedule): BK=64, 256 thr,
// double-buffered counted-vmcnt, XOR swizzle, XCD swizzle.  Runtime row
// strides ldA/ldB (for strided P in PV).  C = sum_p A_p @ B_p^T.
// ---------------------------------------------------------------------------
#define EPI_F32 0
#define EPI_SPLIT16 1
#define EPI_TRANS16 2

template <int EPI, int NPAIR, int KTILES>
__global__ __launch_bounds__(256, 2) void gemm128h(
    const f16* __restrict__ A0, const f16* __restrict__ A1,
    const f16* __restrict__ B0a, const f16* __restrict__ B1a,
    const f16* __restrict__ B0b, const f16* __restrict__ B1b,
    int ysplit, int N, int ldA, int ldB, float scale,
    void* out0a, void* out1a, void* out0b, void* out1b) {
    __shared__ __align__(16) f16 As[2][128 * 64];
    __shared__ __align__(16) f16 Bs[2][128 * 64];

    const int tid = threadIdx.x;
    const int lane = tid & 63;
    const int wid = tid >> 6;
    const int wr = wid >> 1, wc = wid & 1;

    const int total = (int)(gridDim.y << 5);
    int lid = (int)blockIdx.y * 32 + (int)blockIdx.x;
    lid = (lid & 7) * (total >> 3) + (lid >> 3);
    const int bx = lid & 31;
    int by = lid >> 5;

    const f16 *B0, *B1;
    void *o0, *o1;
    if (by >= ysplit) {
        by -= ysplit;
        B0 = B0b; B1 = B1b;
        o0 = out0b; o1 = out1b;
    } else {
        B0 = B0a; B1 = B1a;
        o0 = out0a; o1 = out1a;
    }
    const int m0 = bx * 128;
    const int n0 = by * 128;

    const f16* APs[2] = {A0, A1};
    const f16* BPs[2] = {B0, B1};
    const int nt = NPAIR * KTILES;

    f32x4 acc[4][4];
#pragma unroll
    for (int i = 0; i < 4; ++i)
#pragma unroll
        for (int j = 0; j < 4; ++j) acc[i][j] = (f32x4){0.f, 0.f, 0.f, 0.f};

    auto STAGE = [&](int t, int b) {
        const int pass = t / KTILES;
        const int k0 = (t % KTILES) * 64;
        const f16* Ap = APs[pass];
        const f16* Bp = BPs[pass];
#pragma unroll
        for (int L = 0; L < 4; ++L) {
            const int idx = L * 256 + tid;
            const int row = idx >> 3;
            const int sc = ((idx & 7) * 16) ^ ((row & 7) << 4);
            const int ldsu = (L * 256 + (tid & ~63)) * 8;
            GLOAD_LDS16(Ap + (size_t)(m0 + row) * ldA + k0 + (sc >> 1),
                        &As[b][ldsu]);
            GLOAD_LDS16(Bp + (size_t)(n0 + row) * ldB + k0 + (sc >> 1),
                        &Bs[b][ldsu]);
        }
    };

    STAGE(0, 0);

    for (int t = 0; t < nt; ++t) {
        const int cur = t & 1;
        __builtin_amdgcn_s_barrier();
        asm volatile("" ::: "memory");
        if (t + 1 < nt) {
            STAGE(t + 1, cur ^ 1);
            asm volatile("s_waitcnt vmcnt(8)" ::: "memory");
        } else {
            asm volatile("s_waitcnt vmcnt(0)" ::: "memory");
        }
        __builtin_amdgcn_s_barrier();
        asm volatile("" ::: "memory");

#pragma unroll
        for (int kk = 0; kk < 2; ++kk) {
            const int cb = kk * 64 + (lane >> 4) * 16;
            f16x8 af[4], bv[4];
#pragma unroll
            for (int i = 0; i < 4; ++i) {
                const int r = wr * 64 + i * 16 + (lane & 15);
                af[i] = *(const f16x8*)(&As[cur][r * 64 +
                                                 ((cb ^ ((r & 7) << 4)) >> 1)]);
            }
#pragma unroll
            for (int j = 0; j < 4; ++j) {
                const int r = wc * 64 + j * 16 + (lane & 15);
                bv[j] = *(const f16x8*)(&Bs[cur][r * 64 +
                                                 ((cb ^ ((r & 7) << 4)) >> 1)]);
            }
            __builtin_amdgcn_s_setprio(1);
#pragma unroll
            for (int i = 0; i < 4; ++i)
#pragma unroll
                for (int j = 0; j < 4; ++j)
                    acc[i][j] = __builtin_amdgcn_mfma_f32_16x16x32_f16(
                        af[i], bv[j], acc[i][j], 0, 0, 0);
            __builtin_amdgcn_s_setprio(0);
        }
    }

    const int row0 = m0 + wr * 64 + (lane >> 4) * 4;
    const int col0 = n0 + wc * 64 + (lane & 15);

    if (EPI == EPI_F32) {
        float* O = (float*)o0;
#pragma unroll
        for (int i = 0; i < 4; ++i)
#pragma unroll
            for (int j = 0; j < 4; ++j)
#pragma unroll
                for (int q = 0; q < 4; ++q)
                    O[(size_t)(row0 + i * 16 + q) * N + col0 + j * 16] =
                        acc[i][j][q] * scale;
    } else if (EPI == EPI_SPLIT16) {
        f16* Hi = (f16*)o0;
        f16* Lo = (f16*)o1;
#pragma unroll
        for (int i = 0; i < 4; ++i)
#pragma unroll
            for (int j = 0; j < 4; ++j)
#pragma unroll
                for (int q = 0; q < 4; ++q) {
                    const float x = acc[i][j][q];
                    const f16 h = (f16)x;
                    const size_t idx = (size_t)(row0 + i * 16 + q) * N + col0 + j * 16;
                    Hi[idx] = h;
                    Lo[idx] = (f16)(x - (float)h);
                }
    } else {  // EPI_TRANS16: out[col][row] over SEQ rows
        f16* OT = (f16*)o0;
#pragma unroll
        for (int i = 0; i < 4; ++i)
#pragma unroll
            for (int j = 0; j < 4; ++j) {
                f16x4 v;
#pragma unroll
                for (int q = 0; q < 4; ++q) v[q] = (f16)acc[i][j][q];
                *(f16x4*)&OT[(size_t)(col0 + j * 16) * SEQ + row0 + i * 16] = v;
            }
    }
}

// ---------------------------------------------------------------------------
// QK~ 256x256 fp16 GEMM (round-4 proven schedule) + exact rank-1 epilogue:
//   S = (acc + sx[m]*(256*sx[n] + 0.5*rk[n]) + rq[m]*0.5*sx[n]) * scale
// 2-pass: (Qh,Kh),(Ql,Kh) -> acc = (Qh+Ql)@Kh^T.
// ---------------------------------------------------------------------------
template <int NPAIR, int KT>
__global__ __launch_bounds__(512, 2) void qkrank1(
    const f16* __restrict__ A0, const f16* __restrict__ B0,
    const f16* __restrict__ A1, const f16* __restrict__ B1,
    const float* __restrict__ sx, const float* __restrict__ rq,
    const float* __restrict__ rk,
    int N, float scale, float* __restrict__ out) {
    constexpr int K = KT * 64;
    constexpr int nt = NPAIR * KT;
    __shared__ __align__(16) f16 As[2][256 * 64];   // 64 KB
    __shared__ __align__(16) f16 Bs[2][256 * 64];   // 64 KB

    const int tid = threadIdx.x;
    const int lane = tid & 63;
    const int wid = tid >> 6;
    const int wr = wid >> 2;
    const int wc = wid & 3;

    const int wg = ((int)blockIdx.x & 7) * 32 + ((int)blockIdx.x >> 3);
    const int m0 = (wg >> 4) * 256;
    const int n0 = (wg & 15) * 256;

    const f16* APs[2] = {A0, A1};
    const f16* BPs[2] = {B0, B1};

    f32x4 acc[8][4];
#pragma unroll
    for (int i = 0; i < 8; ++i)
#pragma unroll
        for (int j = 0; j < 4; ++j) acc[i][j] = (f32x4){0.f, 0.f, 0.f, 0.f};

    auto STAGE = [&](int t, int b) {
        const f16* Ap = APs[t / KT];
        const f16* Bp = BPs[t / KT];
        const int k0 = (t % KT) * 64;
#pragma unroll
        for (int L = 0; L < 4; ++L) {
            const int idx = L * 512 + tid;
            const int row = idx >> 3;
            const int sc = ((idx & 7) * 16) ^ ((row & 7) << 4);
            const int ldsu = (L * 512 + (tid & ~63)) * 8;
            GLOAD_LDS16(Ap + (size_t)(m0 + row) * K + k0 + (sc >> 1),
                        &As[b][ldsu]);
            GLOAD_LDS16(Bp + (size_t)(n0 + row) * K + k0 + (sc >> 1),
                        &Bs[b][ldsu]);
        }
    };

    STAGE(0, 0);

    for (int t = 0; t < nt; ++t) {
        const int cur = t & 1;
        __builtin_amdgcn_s_barrier();
        asm volatile("" ::: "memory");
        if (t + 1 < nt) {
            STAGE(t + 1, cur ^ 1);
            asm volatile("s_waitcnt vmcnt(8)" ::: "memory");
        } else {
            asm volatile("s_waitcnt vmcnt(0)" ::: "memory");
        }
        __builtin_amdgcn_s_barrier();
        asm volatile("" ::: "memory");

#pragma unroll
        for (int kk = 0; kk < 2; ++kk) {
            const int cb = kk * 64 + (lane >> 4) * 16;
            f16x8 af[8], bv[4];
#pragma unroll
            for (int i = 0; i < 8; ++i) {
                const int r = wr * 128 + i * 16 + (lane & 15);
                af[i] = *(const f16x8*)(&As[cur][r * 64 +
                                                 ((cb ^ ((r & 7) << 4)) >> 1)]);
            }
#pragma unroll
            for (int j = 0; j < 4; ++j) {
                const int r = wc * 64 + j * 16 + (lane & 15);
                bv[j] = *(const f16x8*)(&Bs[cur][r * 64 +
                                                 ((cb ^ ((r & 7) << 4)) >> 1)]);
            }
            __builtin_amdgcn_s_setprio(1);
#pragma unroll
            for (int i = 0; i < 8; ++i)
#pragma unroll
                for (int j = 0; j < 4; ++j)
                    acc[i][j] = __builtin_amdgcn_mfma_f32_16x16x32_f16(
                        af[i], bv[j], acc[i][j], 0, 0, 0);
            __builtin_amdgcn_s_setprio(0);
        }
    }

    // Epilogue with exact rank-1 terms.
    const int row0 = m0 + wr * 128 + (lane >> 4) * 4;
    const int col0 = n0 + wc * 64 + (lane & 15);
    float u[4], w4[4];
#pragma unroll
    for (int j = 0; j < 4; ++j) {
        const float sxc = sx[col0 + j * 16];
        u[j] = 256.f * sxc + 0.5f * rk[col0 + j * 16];
        w4[j] = 0.5f * sxc;
    }
#pragma unroll
    for (int i = 0; i < 8; ++i)
#pragma unroll
        for (int q = 0; q < 4; ++q) {
            const int r = row0 + i * 16 + q;
            const float sxr = sx[r];
            const float rqr = rq[r];
#pragma unroll
            for (int j = 0; j < 4; ++j)
                out[(size_t)r * N + col0 + j * 16] =
                    (acc[i][j][q] + sxr * u[j] + rqr * w4[j]) * scale;
        }
}

// ---------------------------------------------------------------------------
// Row softmax, in-place P: reads f32 row of S, writes fp16 P over the first
// half of the same row (row stride stays 16384 B = 8192 f16 elements).
// ---------------------------------------------------------------------------
__global__ __launch_bounds__(256) void softmax16(float* __restrict__ S) {
    __shared__ float red[8];
    const int tid = threadIdx.x;
    const size_t row = blockIdx.x;
    const float4* s4 = (const float4*)(S + row * SEQ);

    float4 v[4];
    float mx = -1e30f;
#pragma unroll
    for (int c = 0; c < 4; ++c) {
        v[c] = s4[c * 256 + tid];
        mx = fmaxf(mx, fmaxf(fmaxf(v[c].x, v[c].y), fmaxf(v[c].z, v[c].w)));
    }
#pragma unroll
    for (int m = 32; m >= 1; m >>= 1) mx = fmaxf(mx, __shfl_xor(mx, m));
    if ((tid & 63) == 0) red[tid >> 6] = mx;
    __syncthreads();
    mx = fmaxf(fmaxf(red[0], red[1]), fmaxf(red[2], red[3]));

    float e[16];
    float sum = 0.f;
#pragma unroll
    for (int c = 0; c < 4; ++c) {
        e[c * 4 + 0] = __expf(v[c].x - mx);
        e[c * 4 + 1] = __expf(v[c].y - mx);
        e[c * 4 + 2] = __expf(v[c].z - mx);
        e[c * 4 + 3] = __expf(v[c].w - mx);
        sum += e[c * 4] + e[c * 4 + 1] + e[c * 4 + 2] + e[c * 4 + 3];
    }
#pragma unroll
    for (int m = 32; m >= 1; m >>= 1) sum += __shfl_xor(sum, m);
    if ((tid & 63) == 0) red[4 + (tid >> 6)] = sum;
    __syncthreads();
    sum = red[4] + red[5] + red[6] + red[7];
    const float inv = 1.f / sum;

    f16* prow = (f16*)(S + row * SEQ);   // first 8 KB of this 16 KB row
#pragma unroll
    for (int c = 0; c < 4; ++c) {
        f16x4 o;
#pragma unroll
        for (int q = 0; q < 4; ++q) o[q] = (f16)(e[c * 4 + q] * inv);
        ((f16x4*)prow)[c * 256 + tid] = o;
    }
}

// ---------------------------------------------------------------------------
extern "C" void kernel_launch(void* const* d_in, const int* in_sizes, int n_in,
                              void* d_out, int out_size, void* d_ws, size_t ws_size,
                              hipStream_t stream) {
    const float* x  = (const float*)d_in[0];
    const float* wq = (const float*)d_in[1];
    const float* wk = (const float*)d_in[2];
    const float* wv = (const float*)d_in[3];
    float* O = (float*)d_out;

    char* ws = (char*)d_ws;
    const size_t MB = 1024 * 1024;
    const size_t KB = 1024;
    f16* Qh = (f16*)(ws + 0 * MB);        // live: proj -> qk
    f16* Ql = (f16*)(ws + 8 * MB);
    f16* Kh = (f16*)(ws + 16 * MB);
    f16* VT = (f16*)(ws + 24 * MB);       // live: vproj -> pv
    float* sx = (float*)(ws + 32 * MB);   // 16 KB each, live -> qk
    float* rq = (float*)(ws + 32 * MB + 16 * KB);
    float* rk = (float*)(ws + 32 * MB + 32 * KB);
    float* S  = (float*)(ws + 40 * MB);   // 64 MB; P written in-place by softmax
    // Dead-before-S region (all consumed before qkrank1 writes S):
    f16* Xh  = (f16*)(ws + 40 * MB);
    f16* Xl  = (f16*)(ws + 48 * MB);
    f16* Wqh = (f16*)(ws + 56 * MB);
    f16* Wkh = (f16*)(ws + 58 * MB);
    f16* Wvh = (f16*)(ws + 60 * MB);
    f16* Kl  = (f16*)(ws + 64 * MB);      // read only by rowsum_hl

    split16<<<4096, 256, 0, stream>>>(x, Xh, Xl, SEQ * DIM / 4);
    wtrans3h<<<dim3(DIM / 32, DIM / 32, 3), 256, 0, stream>>>(
        wq, wk, wv, Wqh, Wkh, Wvh);
    rowsum_x<<<1024, 256, 0, stream>>>(x, sx);

    // Q~ and K~ projections, 2-pass fp16 ((Xh+Xl)@W~h), merged dispatch.
    gemm128h<EPI_SPLIT16, 2, 16><<<dim3(32, 16), 256, 0, stream>>>(
        Xh, Xl, Wqh, Wqh, Wkh, Wkh,
        8, DIM, DIM, DIM, 1.f, Qh, Ql, Kh, Kl);

    rowsum_hl<<<dim3(1024, 2), 256, 0, stream>>>(Qh, Ql, Kh, Kl, rq, rk);

    // V projection (single-pass fp16, transposed store).
    gemm128h<EPI_TRANS16, 1, 16><<<dim3(32, 8), 256, 0, stream>>>(
        Xh, Xh, Wvh, Wvh, Wvh, Wvh,
        8, DIM, DIM, DIM, 1.f, VT, nullptr, VT, nullptr);

    // S = ((Qh+Ql)@Kh^T + rank-1 terms) / 32.
    qkrank1<2, 16><<<256, 512, 0, stream>>>(
        Qh, Kh, Ql, Kh, sx, rq, rk, SEQ, 0.03125f, S);

    softmax16<<<SEQ, 256, 0, stream>>>(S);

    // O = P @ V;  P is fp16 rows at stride 8192 inside S.
    gemm128h<EPI_F32, 1, 64><<<dim3(32, 8), 256, 0, stream>>>(
        (const f16*)S, (const f16*)S, VT, VT, VT, VT,
        8, DIM, 2 * SEQ, SEQ, 1.f, O, nullptr, O, nullptr);
}

// Round 10
// 235.222 us; speedup vs baseline: 1.2620x; 1.0072x over previous
//
#include <hip/hip_runtime.h>
#include <math.h>

#define SEQ 4096
#define DIM 1024

typedef _Float16 f16;
typedef _Float16 f16x8 __attribute__((ext_vector_type(8)));
typedef _Float16 f16x4 __attribute__((ext_vector_type(4)));
typedef float f32x4 __attribute__((ext_vector_type(4)));

#define GLOAD_LDS16(g, l)                                              \
    __builtin_amdgcn_global_load_lds(                                  \
        (const __attribute__((address_space(1))) void*)(g),            \
        (__attribute__((address_space(3))) void*)(l), 16, 0, 0)

// ---------------------------------------------------------------------------
// Split f32 -> (hi, lo) fp16 + per-row sum.  One block == one row (DIM=1024).
// ---------------------------------------------------------------------------
__global__ __launch_bounds__(256) void split16rs(const float* __restrict__ in,
                                                 f16* __restrict__ hi,
                                                 f16* __restrict__ lo,
                                                 float* __restrict__ sx) {
    __shared__ float sred[4];
    const int tid = threadIdx.x;
    const int i = blockIdx.x * 256 + tid;
    const float4 v = ((const float4*)in)[i];
    const float vv[4] = {v.x, v.y, v.z, v.w};
    f16x4 h, l;
#pragma unroll
    for (int q = 0; q < 4; ++q) {
        const f16 hq = (f16)vv[q];
        h[q] = hq;
        l[q] = (f16)(vv[q] - (float)hq);
    }
    ((f16x4*)hi)[i] = h;
    ((f16x4*)lo)[i] = l;
    float s = v.x + v.y + v.z + v.w;
#pragma unroll
    for (int m = 32; m >= 1; m >>= 1) s += __shfl_xor(s, m);
    if ((tid & 63) == 0) sred[tid >> 6] = s;
    __syncthreads();
    if (tid == 0) sx[blockIdx.x] = sred[0] + sred[1] + sred[2] + sred[3];
}

// ---------------------------------------------------------------------------
// Transpose-convert weights -> W^T fp16.  z=0: wq-0.5, z=1: wk-0.5, z=2: wv.
// ---------------------------------------------------------------------------
__global__ __launch_bounds__(256) void wtrans3h(
    const float* __restrict__ Wq, const float* __restrict__ Wk,
    const float* __restrict__ Wv,
    f16* __restrict__ QT, f16* __restrict__ KT, f16* __restrict__ VT) {
    __shared__ float tile[32][33];
    const int tid = threadIdx.x;
    const int r0 = blockIdx.x * 32;  // W row (k)
    const int c0 = blockIdx.y * 32;  // W col (n)
    const int z = blockIdx.z;
    const float* W = (z == 0) ? Wq : (z == 1) ? Wk : Wv;
    f16* T = (z == 0) ? QT : (z == 1) ? KT : VT;
    const float off = (z < 2) ? 0.5f : 0.0f;
    {
        const int r = tid >> 3, c = (tid & 7) * 4;
        const float4 v = *(const float4*)&W[(size_t)(r0 + r) * DIM + c0 + c];
        tile[r][c + 0] = v.x;
        tile[r][c + 1] = v.y;
        tile[r][c + 2] = v.z;
        tile[r][c + 3] = v.w;
    }
    __syncthreads();
    {
        const int n = tid >> 3;
        const int k = (tid & 7) * 4;
        f16x4 h;
#pragma unroll
        for (int q = 0; q < 4; ++q) h[q] = (f16)(tile[k + q][n] - off);
        *(f16x4*)&T[(size_t)(c0 + n) * DIM + r0 + k] = h;
    }
}

// ---------------------------------------------------------------------------
// rq[m] = rowsum(Qh+Ql); rk[m] = rowsum(Kh+Kl).  y=0 -> Q, y=1 -> K.
// ---------------------------------------------------------------------------
__global__ __launch_bounds__(256) void rowsum_hl(
    const f16* __restrict__ Qh, const f16* __restrict__ Ql,
    const f16* __restrict__ Kh, const f16* __restrict__ Kl,
    float* __restrict__ rq, float* __restrict__ rk) {
    const f16 *H, *L;
    float* out;
    if (blockIdx.y == 0) { H = Qh; L = Ql; out = rq; }
    else                 { H = Kh; L = Kl; out = rk; }
    const int row = blockIdx.x * 4 + (threadIdx.x >> 6);
    const int lane = threadIdx.x & 63;
    const f16x8* h8 = (const f16x8*)(H + (size_t)row * DIM);
    const f16x8* l8 = (const f16x8*)(L + (size_t)row * DIM);
    float s = 0.f;
#pragma unroll
    for (int c = 0; c < 2; ++c) {
        const f16x8 a = h8[lane + 64 * c];
        const f16x8 b = l8[lane + 64 * c];
#pragma unroll
        for (int e = 0; e < 8; ++e) s += (float)a[e] + (float)b[e];
    }
#pragma unroll
    for (int m = 32; m >= 1; m >>= 1) s += __shfl_xor(s, m);
    if (lane == 0) out[row] = s;
}

// ---------------------------------------------------------------------------
// 128x128 fp16 MFMA GEMM (proven schedule): BK=64, 256 thr, double-buffered
// counted-vmcnt, XOR swizzle, XCD swizzle.  Runtime strides ldA/ldB.
// ---------------------------------------------------------------------------
#define EPI_F32 0
#define EPI_SPLIT16 1
#define EPI_TRANS16 2

template <int EPI, int NPAIR, int KTILES>
__global__ __launch_bounds__(256, 2) void gemm128h(
    const f16* __restrict__ A0, const f16* __restrict__ A1,
    const f16* __restrict__ B0a, const f16* __restrict__ B1a,
    const f16* __restrict__ B0b, const f16* __restrict__ B1b,
    int ysplit, int N, int ldA, int ldB, float scale,
    void* out0a, void* out1a, void* out0b, void* out1b) {
    __shared__ __align__(16) f16 As[2][128 * 64];
    __shared__ __align__(16) f16 Bs[2][128 * 64];

    const int tid = threadIdx.x;
    const int lane = tid & 63;
    const int wid = tid >> 6;
    const int wr = wid >> 1, wc = wid & 1;

    const int total = (int)(gridDim.y << 5);
    int lid = (int)blockIdx.y * 32 + (int)blockIdx.x;
    lid = (lid & 7) * (total >> 3) + (lid >> 3);
    const int bx = lid & 31;
    int by = lid >> 5;

    const f16 *B0, *B1;
    void *o0, *o1;
    if (by >= ysplit) {
        by -= ysplit;
        B0 = B0b; B1 = B1b;
        o0 = out0b; o1 = out1b;
    } else {
        B0 = B0a; B1 = B1a;
        o0 = out0a; o1 = out1a;
    }
    const int m0 = bx * 128;
    const int n0 = by * 128;

    const f16* APs[2] = {A0, A1};
    const f16* BPs[2] = {B0, B1};
    const int nt = NPAIR * KTILES;

    f32x4 acc[4][4];
#pragma unroll
    for (int i = 0; i < 4; ++i)
#pragma unroll
        for (int j = 0; j < 4; ++j) acc[i][j] = (f32x4){0.f, 0.f, 0.f, 0.f};

    auto STAGE = [&](int t, int b) {
        const int pass = t / KTILES;
        const int k0 = (t % KTILES) * 64;
        const f16* Ap = APs[pass];
        const f16* Bp = BPs[pass];
#pragma unroll
        for (int L = 0; L < 4; ++L) {
            const int idx = L * 256 + tid;
            const int row = idx >> 3;
            const int sc = ((idx & 7) * 16) ^ ((row & 7) << 4);
            const int ldsu = (L * 256 + (tid & ~63)) * 8;
            GLOAD_LDS16(Ap + (size_t)(m0 + row) * ldA + k0 + (sc >> 1),
                        &As[b][ldsu]);
            GLOAD_LDS16(Bp + (size_t)(n0 + row) * ldB + k0 + (sc >> 1),
                        &Bs[b][ldsu]);
        }
    };

    STAGE(0, 0);

    for (int t = 0; t < nt; ++t) {
        const int cur = t & 1;
        __builtin_amdgcn_s_barrier();
        asm volatile("" ::: "memory");
        if (t + 1 < nt) {
            STAGE(t + 1, cur ^ 1);
            asm volatile("s_waitcnt vmcnt(8)" ::: "memory");
        } else {
            asm volatile("s_waitcnt vmcnt(0)" ::: "memory");
        }
        __builtin_amdgcn_s_barrier();
        asm volatile("" ::: "memory");

#pragma unroll
        for (int kk = 0; kk < 2; ++kk) {
            const int cb = kk * 64 + (lane >> 4) * 16;
            f16x8 af[4], bv[4];
#pragma unroll
            for (int i = 0; i < 4; ++i) {
                const int r = wr * 64 + i * 16 + (lane & 15);
                af[i] = *(const f16x8*)(&As[cur][r * 64 +
                                                 ((cb ^ ((r & 7) << 4)) >> 1)]);
            }
#pragma unroll
            for (int j = 0; j < 4; ++j) {
                const int r = wc * 64 + j * 16 + (lane & 15);
                bv[j] = *(const f16x8*)(&Bs[cur][r * 64 +
                                                 ((cb ^ ((r & 7) << 4)) >> 1)]);
            }
            __builtin_amdgcn_s_setprio(1);
#pragma unroll
            for (int i = 0; i < 4; ++i)
#pragma unroll
                for (int j = 0; j < 4; ++j)
                    acc[i][j] = __builtin_amdgcn_mfma_f32_16x16x32_f16(
                        af[i], bv[j], acc[i][j], 0, 0, 0);
            __builtin_amdgcn_s_setprio(0);
        }
    }

    const int row0 = m0 + wr * 64 + (lane >> 4) * 4;
    const int col0 = n0 + wc * 64 + (lane & 15);

    if (EPI == EPI_F32) {
        float* O = (float*)o0;
#pragma unroll
        for (int i = 0; i < 4; ++i)
#pragma unroll
            for (int j = 0; j < 4; ++j)
#pragma unroll
                for (int q = 0; q < 4; ++q)
                    O[(size_t)(row0 + i * 16 + q) * N + col0 + j * 16] =
                        acc[i][j][q] * scale;
    } else if (EPI == EPI_SPLIT16) {
        f16* Hi = (f16*)o0;
        f16* Lo = (f16*)o1;
#pragma unroll
        for (int i = 0; i < 4; ++i)
#pragma unroll
            for (int j = 0; j < 4; ++j)
#pragma unroll
                for (int q = 0; q < 4; ++q) {
                    const float x = acc[i][j][q];
                    const f16 h = (f16)x;
                    const size_t idx = (size_t)(row0 + i * 16 + q) * N + col0 + j * 16;
                    Hi[idx] = h;
                    Lo[idx] = (f16)(x - (float)h);
                }
    } else {  // EPI_TRANS16: out[col][row] over SEQ rows
        f16* OT = (f16*)o0;
#pragma unroll
        for (int i = 0; i < 4; ++i)
#pragma unroll
            for (int j = 0; j < 4; ++j) {
                f16x4 v;
#pragma unroll
                for (int q = 0; q < 4; ++q) v[q] = (f16)acc[i][j][q];
                *(f16x4*)&OT[(size_t)(col0 + j * 16) * SEQ + row0 + i * 16] = v;
            }
    }
}

// ---------------------------------------------------------------------------
// QK~ 256x256 fp16 GEMM + rank-1 epilogue + BLOCK-LOCAL softmax.
// Each block owns one 256-col strip (bcol = n0>>8) of 256 rows.  Epilogue:
//   s = (acc + sx[m]*(256*sx[n]+0.5*rk[n]) + rq[m]*0.5*sx[n]) / 32
//   m_b = rowmax(s) over the strip, Pu = exp(s-m_b) (f16), l_b = rowsum.
// Writes Pu [SEQ][SEQ] f16, Mp/Lp [SEQ][16] f32.  Main loop = proven 256².
// ---------------------------------------------------------------------------
template <int NPAIR, int KT>
__global__ __launch_bounds__(512, 2) void qkrank1(
    const f16* __restrict__ A0, const f16* __restrict__ B0,
    const f16* __restrict__ A1, const f16* __restrict__ B1,
    const float* __restrict__ sx, const float* __restrict__ rq,
    const float* __restrict__ rk,
    f16* __restrict__ Pu, float* __restrict__ Mp, float* __restrict__ Lp) {
    constexpr int K = KT * 64;
    constexpr int nt = NPAIR * KT;
    __shared__ __align__(16) f16 As[2][256 * 64];   // 64 KB
    __shared__ __align__(16) f16 Bs[2][256 * 64];   // 64 KB

    const int tid = threadIdx.x;
    const int lane = tid & 63;
    const int wid = tid >> 6;
    const int wr = wid >> 2;
    const int wc = wid & 3;

    const int wg = ((int)blockIdx.x & 7) * 32 + ((int)blockIdx.x >> 3);
    const int m0 = (wg >> 4) * 256;
    const int n0 = (wg & 15) * 256;
    const int bcol = n0 >> 8;

    const f16* APs[2] = {A0, A1};
    const f16* BPs[2] = {B0, B1};

    f32x4 acc[8][4];
#pragma unroll
    for (int i = 0; i < 8; ++i)
#pragma unroll
        for (int j = 0; j < 4; ++j) acc[i][j] = (f32x4){0.f, 0.f, 0.f, 0.f};

    auto STAGE = [&](int t, int b) {
        const f16* Ap = APs[t / KT];
        const f16* Bp = BPs[t / KT];
        const int k0 = (t % KT) * 64;
#pragma unroll
        for (int L = 0; L < 4; ++L) {
            const int idx = L * 512 + tid;
            const int row = idx >> 3;
            const int sc = ((idx & 7) * 16) ^ ((row & 7) << 4);
            const int ldsu = (L * 512 + (tid & ~63)) * 8;
            GLOAD_LDS16(Ap + (size_t)(m0 + row) * K + k0 + (sc >> 1),
                        &As[b][ldsu]);
            GLOAD_LDS16(Bp + (size_t)(n0 + row) * K + k0 + (sc >> 1),
                        &Bs[b][ldsu]);
        }
    };

    STAGE(0, 0);

    for (int t = 0; t < nt; ++t) {
        const int cur = t & 1;
        __builtin_amdgcn_s_barrier();
        asm volatile("" ::: "memory");
        if (t + 1 < nt) {
            STAGE(t + 1, cur ^ 1);
            asm volatile("s_waitcnt vmcnt(8)" ::: "memory");
        } else {
            asm volatile("s_waitcnt vmcnt(0)" ::: "memory");
        }
        __builtin_amdgcn_s_barrier();
        asm volatile("" ::: "memory");

#pragma unroll
        for (int kk = 0; kk < 2; ++kk) {
            const int cb = kk * 64 + (lane >> 4) * 16;
            f16x8 af[8], bv[4];
#pragma unroll
            for (int i = 0; i < 8; ++i) {
                const int r = wr * 128 + i * 16 + (lane & 15);
                af[i] = *(const f16x8*)(&As[cur][r * 64 +
                                                 ((cb ^ ((r & 7) << 4)) >> 1)]);
            }
#pragma unroll
            for (int j = 0; j < 4; ++j) {
                const int r = wc * 64 + j * 16 + (lane & 15);
                bv[j] = *(const f16x8*)(&Bs[cur][r * 64 +
                                                 ((cb ^ ((r & 7) << 4)) >> 1)]);
            }
            __builtin_amdgcn_s_setprio(1);
#pragma unroll
            for (int i = 0; i < 8; ++i)
#pragma unroll
                for (int j = 0; j < 4; ++j)
                    acc[i][j] = __builtin_amdgcn_mfma_f32_16x16x32_f16(
                        af[i], bv[j], acc[i][j], 0, 0, 0);
            __builtin_amdgcn_s_setprio(0);
        }
    }

    // ---- epilogue: rank-1 + scale (in place) ----
    const int g4 = lane >> 4;
    const int l15 = lane & 15;
    const int row0 = m0 + wr * 128 + g4 * 4;   // + i*16 + q
    const int col0 = n0 + wc * 64 + l15;       // + j*16
    float u[4], w4[4];
#pragma unroll
    for (int j = 0; j < 4; ++j) {
        const float sxc = sx[col0 + j * 16];
        u[j] = 256.f * sxc + 0.5f * rk[col0 + j * 16];
        w4[j] = 0.5f * sxc;
    }
#pragma unroll
    for (int i = 0; i < 8; ++i)
#pragma unroll
        for (int q = 0; q < 4; ++q) {
            const int r = row0 + i * 16 + q;
            const float sxr = sx[r];
            const float rqr = rq[r];
#pragma unroll
            for (int j = 0; j < 4; ++j)
                acc[i][j][q] =
                    (acc[i][j][q] + sxr * u[j] + rqr * w4[j]) * 0.03125f;
        }

    // ---- block-local softmax over the 256-col strip ----
    // LDS scratch overlays As[0] (all LDS reads completed; see barriers).
    float* partm = (float*)&As[0][0];      // [256][4]
    float* mrow  = partm + 1024;           // [256]
    float* parts = mrow + 256;             // [256][4]
    float red[8][4];
#pragma unroll
    for (int i = 0; i < 8; ++i)
#pragma unroll
        for (int q = 0; q < 4; ++q) {
            float v = acc[i][0][q];
#pragma unroll
            for (int j = 1; j < 4; ++j) v = fmaxf(v, acc[i][j][q]);
            red[i][q] = v;
        }
#pragma unroll
    for (int msk = 1; msk < 16; msk <<= 1)
#pragma unroll
        for (int i = 0; i < 8; ++i)
#pragma unroll
            for (int q = 0; q < 4; ++q)
                red[i][q] = fmaxf(red[i][q], __shfl_xor(red[i][q], msk));
    __syncthreads();
    if (l15 == 0)
#pragma unroll
        for (int i = 0; i < 8; ++i)
#pragma unroll
            for (int q = 0; q < 4; ++q)
                partm[(wr * 128 + i * 16 + g4 * 4 + q) * 4 + wc] = red[i][q];
    __syncthreads();
    if (tid < 256) {
        const float* p = partm + tid * 4;
        mrow[tid] = fmaxf(fmaxf(p[0], p[1]), fmaxf(p[2], p[3]));
    }
    __syncthreads();
#pragma unroll
    for (int i = 0; i < 8; ++i)
#pragma unroll
        for (int q = 0; q < 4; ++q) {
            const float mB = mrow[wr * 128 + i * 16 + g4 * 4 + q];
            float s = 0.f;
#pragma unroll
            for (int j = 0; j < 4; ++j) {
                const float e = __expf(acc[i][j][q] - mB);
                acc[i][j][q] = e;
                s += e;
            }
            red[i][q] = s;
        }
#pragma unroll
    for (int msk = 1; msk < 16; msk <<= 1)
#pragma unroll
        for (int i = 0; i < 8; ++i)
#pragma unroll
            for (int q = 0; q < 4; ++q) red[i][q] += __shfl_xor(red[i][q], msk);
    if (l15 == 0)
#pragma unroll
        for (int i = 0; i < 8; ++i)
#pragma unroll
            for (int q = 0; q < 4; ++q)
                parts[(wr * 128 + i * 16 + g4 * 4 + q) * 4 + wc] = red[i][q];
    __syncthreads();
    if (tid < 256) {
        const float* p = parts + tid * 4;
        Mp[(size_t)(m0 + tid) * 16 + bcol] = mrow[tid];
        Lp[(size_t)(m0 + tid) * 16 + bcol] = p[0] + p[1] + p[2] + p[3];
    }
    // ---- write Pu (f16) ----
#pragma unroll
    for (int i = 0; i < 8; ++i)
#pragma unroll
        for (int q = 0; q < 4; ++q) {
            const size_t r = row0 + i * 16 + q;
#pragma unroll
            for (int j = 0; j < 4; ++j)
                Pu[r * SEQ + col0 + j * 16] = (f16)acc[i][j][q];
        }
}

// ---------------------------------------------------------------------------
// rowfix: per row combine the 16 block-local (m_b, l_b), then rescale the Pu
// row in place by exp(m_b - m)/l  ->  fully-normalized P.
// ---------------------------------------------------------------------------
__global__ __launch_bounds__(256) void rowfix(const float* __restrict__ Mp,
                                              const float* __restrict__ Lp,
                                              f16* __restrict__ Pu) {
    __shared__ float mls[32];
    const int tid = threadIdx.x;
    const size_t r = blockIdx.x;
    if (tid < 32)
        mls[tid] = (tid < 16) ? Mp[r * 16 + tid] : Lp[r * 16 + tid - 16];
    __syncthreads();
    float m = -1e30f;
#pragma unroll
    for (int b = 0; b < 16; ++b) m = fmaxf(m, mls[b]);
    float l = 0.f;
#pragma unroll
    for (int b = 0; b < 16; ++b) l += __expf(mls[b] - m) * mls[16 + b];
    const float inv = 1.f / l;

    f16* row = Pu + r * SEQ;
#pragma unroll
    for (int p = 0; p < 2; ++p) {
        const int c0 = p * 2048 + tid * 8;
        const float d = __expf(mls[c0 >> 8] - m) * inv;   // LDS dynamic idx OK
        f16x8 v = *(const f16x8*)(row + c0);
#pragma unroll
        for (int e = 0; e < 8; ++e) v[e] = (f16)((float)v[e] * d);
        *(f16x8*)(row + c0) = v;
    }
}

// ---------------------------------------------------------------------------
extern "C" void kernel_launch(void* const* d_in, const int* in_sizes, int n_in,
                              void* d_out, int out_size, void* d_ws, size_t ws_size,
                              hipStream_t stream) {
    const float* x  = (const float*)d_in[0];
    const float* wq = (const float*)d_in[1];
    const float* wk = (const float*)d_in[2];
    const float* wv = (const float*)d_in[3];
    float* O = (float*)d_out;

    char* ws = (char*)d_ws;
    const size_t MB = 1024 * 1024;
    const size_t KB = 1024;
    f16* Qh = (f16*)(ws + 0 * MB);        // live: proj -> qk
    f16* Ql = (f16*)(ws + 8 * MB);
    f16* Kh = (f16*)(ws + 16 * MB);
    f16* VT = (f16*)(ws + 24 * MB);       // live: vproj -> pv
    float* sx = (float*)(ws + 32 * MB);   // scalars region 32..33 MB
    float* rq = (float*)(ws + 32 * MB + 16 * KB);
    float* rk = (float*)(ws + 32 * MB + 32 * KB);
    float* Mp = (float*)(ws + 32 * MB + 48 * KB);    // [4096][16]
    float* Lp = (float*)(ws + 32 * MB + 304 * KB);   // [4096][16]
    f16* Pu = (f16*)(ws + 40 * MB);       // 32 MB, written by qkrank1
    // Dead-before-Pu region (all consumed before qkrank1 writes):
    f16* Xh  = (f16*)(ws + 40 * MB);
    f16* Xl  = (f16*)(ws + 48 * MB);
    f16* Wqh = (f16*)(ws + 56 * MB);
    f16* Wkh = (f16*)(ws + 58 * MB);
    f16* Wvh = (f16*)(ws + 60 * MB);
    f16* Kl  = (f16*)(ws + 64 * MB);      // read only by rowsum_hl

    split16rs<<<4096, 256, 0, stream>>>(x, Xh, Xl, sx);
    wtrans3h<<<dim3(DIM / 32, DIM / 32, 3), 256, 0, stream>>>(
        wq, wk, wv, Wqh, Wkh, Wvh);

    // Q~ and K~ projections, 2-pass fp16 ((Xh+Xl)@W~h), merged dispatch.
    gemm128h<EPI_SPLIT16, 2, 16><<<dim3(32, 16), 256, 0, stream>>>(
        Xh, Xl, Wqh, Wqh, Wkh, Wkh,
        8, DIM, DIM, DIM, 1.f, Qh, Ql, Kh, Kl);

    rowsum_hl<<<dim3(1024, 2), 256, 0, stream>>>(Qh, Ql, Kh, Kl, rq, rk);

    // V projection (single-pass fp16, transposed store).
    gemm128h<EPI_TRANS16, 1, 16><<<dim3(32, 8), 256, 0, stream>>>(
        Xh, Xh, Wvh, Wvh, Wvh, Wvh,
        8, DIM, DIM, DIM, 1.f, VT, nullptr, VT, nullptr);

    // Pu = exp(S - m_b) per 256-col strip + (m_b, l_b) partials.
    qkrank1<2, 16><<<256, 512, 0, stream>>>(
        Qh, Kh, Ql, Kh, sx, rq, rk, Pu, Mp, Lp);

    // Normalize: Pu *= exp(m_b - m)/l  ->  P.
    rowfix<<<4096, 256, 0, stream>>>(Mp, Lp, Pu);

    // O = P @ V  (A = P, ldA = SEQ;  B^T = VT, ldB = SEQ).
    gemm128h<EPI_F32, 1, 64><<<dim3(32, 8), 256, 0, stream>>>(
        Pu, Pu, VT, VT, VT, VT,
        8, DIM, SEQ, SEQ, 1.f, O, nullptr, O, nullptr);
}

// Round 11
// 227.699 us; speedup vs baseline: 1.3036x; 1.0330x over previous
//
#include <hip/hip_runtime.h>
#include <math.h>

#define SEQ 4096
#define DIM 1024

typedef _Float16 f16;
typedef _Float16 f16x8 __attribute__((ext_vector_type(8)));
typedef _Float16 f16x4 __attribute__((ext_vector_type(4)));
typedef float f32x4 __attribute__((ext_vector_type(4)));

#define GLOAD_LDS16(g, l)                                              \
    __builtin_amdgcn_global_load_lds(                                  \
        (const __attribute__((address_space(1))) void*)(g),            \
        (__attribute__((address_space(3))) void*)(l), 16, 0, 0)

// ---------------------------------------------------------------------------
// Split f32 -> (hi, lo) fp16 + per-row sum.  One block == one row (DIM=1024).
// ---------------------------------------------------------------------------
__global__ __launch_bounds__(256) void split16rs(const float* __restrict__ in,
                                                 f16* __restrict__ hi,
                                                 f16* __restrict__ lo,
                                                 float* __restrict__ sx) {
    __shared__ float sred[4];
    const int tid = threadIdx.x;
    const int i = blockIdx.x * 256 + tid;
    const float4 v = ((const float4*)in)[i];
    const float vv[4] = {v.x, v.y, v.z, v.w};
    f16x4 h, l;
#pragma unroll
    for (int q = 0; q < 4; ++q) {
        const f16 hq = (f16)vv[q];
        h[q] = hq;
        l[q] = (f16)(vv[q] - (float)hq);
    }
    ((f16x4*)hi)[i] = h;
    ((f16x4*)lo)[i] = l;
    float s = v.x + v.y + v.z + v.w;
#pragma unroll
    for (int m = 32; m >= 1; m >>= 1) s += __shfl_xor(s, m);
    if ((tid & 63) == 0) sred[tid >> 6] = s;
    __syncthreads();
    if (tid == 0) sx[blockIdx.x] = sred[0] + sred[1] + sred[2] + sred[3];
}

// ---------------------------------------------------------------------------
// Transpose-convert weights -> W^T fp16.  z=0: wq-0.5, z=1: wk-0.5, z=2: wv.
// ---------------------------------------------------------------------------
__global__ __launch_bounds__(256) void wtrans3h(
    const float* __restrict__ Wq, const float* __restrict__ Wk,
    const float* __restrict__ Wv,
    f16* __restrict__ QT, f16* __restrict__ KT, f16* __restrict__ VT) {
    __shared__ float tile[32][33];
    const int tid = threadIdx.x;
    const int r0 = blockIdx.x * 32;  // W row (k)
    const int c0 = blockIdx.y * 32;  // W col (n)
    const int z = blockIdx.z;
    const float* W = (z == 0) ? Wq : (z == 1) ? Wk : Wv;
    f16* T = (z == 0) ? QT : (z == 1) ? KT : VT;
    const float off = (z < 2) ? 0.5f : 0.0f;
    {
        const int r = tid >> 3, c = (tid & 7) * 4;
        const float4 v = *(const float4*)&W[(size_t)(r0 + r) * DIM + c0 + c];
        tile[r][c + 0] = v.x;
        tile[r][c + 1] = v.y;
        tile[r][c + 2] = v.z;
        tile[r][c + 3] = v.w;
    }
    __syncthreads();
    {
        const int n = tid >> 3;
        const int k = (tid & 7) * 4;
        f16x4 h;
#pragma unroll
        for (int q = 0; q < 4; ++q) h[q] = (f16)(tile[k + q][n] - off);
        *(f16x4*)&T[(size_t)(c0 + n) * DIM + r0 + k] = h;
    }
}

// ---------------------------------------------------------------------------
// rq[m] = rowsum(Qh+Ql); rk[m] = rowsum(Kh+Kl).  y=0 -> Q, y=1 -> K.
// ---------------------------------------------------------------------------
__global__ __launch_bounds__(256) void rowsum_hl(
    const f16* __restrict__ Qh, const f16* __restrict__ Ql,
    const f16* __restrict__ Kh, const f16* __restrict__ Kl,
    float* __restrict__ rq, float* __restrict__ rk) {
    const f16 *H, *L;
    float* out;
    if (blockIdx.y == 0) { H = Qh; L = Ql; out = rq; }
    else                 { H = Kh; L = Kl; out = rk; }
    const int row = blockIdx.x * 4 + (threadIdx.x >> 6);
    const int lane = threadIdx.x & 63;
    const f16x8* h8 = (const f16x8*)(H + (size_t)row * DIM);
    const f16x8* l8 = (const f16x8*)(L + (size_t)row * DIM);
    float s = 0.f;
#pragma unroll
    for (int c = 0; c < 2; ++c) {
        const f16x8 a = h8[lane + 64 * c];
        const f16x8 b = l8[lane + 64 * c];
#pragma unroll
        for (int e = 0; e < 8; ++e) s += (float)a[e] + (float)b[e];
    }
#pragma unroll
    for (int m = 32; m >= 1; m >>= 1) s += __shfl_xor(s, m);
    if (lane == 0) out[row] = s;
}

// ---------------------------------------------------------------------------
// Generalized 128x128 fp16 MFMA GEMM (proven round-5 schedule untouched):
// BK=64, 256 thr, double-buffered counted-vmcnt, XOR swizzle, XCD swizzle.
// Up to 3 "sets" selected by by>>3: per-set B pair, outputs, runtime
// epilogue, and per-set A/B element offsets (for split-K).
// ---------------------------------------------------------------------------
#define EPI_F32 0
#define EPI_SPLIT16 1
#define EPI_TRANS16 2

template <int NPAIR, int KTILES>
__global__ __launch_bounds__(256, 2) void gemm128s(
    const f16* __restrict__ A0, const f16* __restrict__ A1, int ldA, int ldB,
    const f16* __restrict__ B0_0, const f16* __restrict__ B1_0,
    void* o0_0, void* o1_0,
    const f16* __restrict__ B0_1, const f16* __restrict__ B1_1,
    void* o0_1, void* o1_1,
    const f16* __restrict__ B0_2, const f16* __restrict__ B1_2,
    void* o0_2, void* o1_2,
    int aoffPerSet, int boffPerSet,
    int epi0, int epi1, int epi2,
    int N, float scale) {
    __shared__ __align__(16) f16 As[2][128 * 64];
    __shared__ __align__(16) f16 Bs[2][128 * 64];

    const int tid = threadIdx.x;
    const int lane = tid & 63;
    const int wid = tid >> 6;
    const int wr = wid >> 1, wc = wid & 1;

    const int total = (int)(gridDim.y << 5);
    int lid = (int)blockIdx.y * 32 + (int)blockIdx.x;
    lid = (lid & 7) * (total >> 3) + (lid >> 3);
    const int bx = lid & 31;
    int by = lid >> 5;

    const int set = by >> 3;
    by &= 7;

    const f16 *B0, *B1;
    void *o0, *o1;
    int epi;
    if (set == 0)      { B0 = B0_0; B1 = B1_0; o0 = o0_0; o1 = o1_0; epi = epi0; }
    else if (set == 1) { B0 = B0_1; B1 = B1_1; o0 = o0_1; o1 = o1_1; epi = epi1; }
    else               { B0 = B0_2; B1 = B1_2; o0 = o0_2; o1 = o1_2; epi = epi2; }
    const int aoff = set * aoffPerSet;
    const int boff = set * boffPerSet;

    const int m0 = bx * 128;
    const int n0 = by * 128;

    const f16* APs[2] = {A0, A1};
    const f16* BPs[2] = {B0, B1};
    const int nt = NPAIR * KTILES;

    f32x4 acc[4][4];
#pragma unroll
    for (int i = 0; i < 4; ++i)
#pragma unroll
        for (int j = 0; j < 4; ++j) acc[i][j] = (f32x4){0.f, 0.f, 0.f, 0.f};

    auto STAGE = [&](int t, int b) {
        const int pass = t / KTILES;
        const int k0 = (t % KTILES) * 64;
        const f16* Ap = APs[pass];
        const f16* Bp = BPs[pass];
#pragma unroll
        for (int L = 0; L < 4; ++L) {
            const int idx = L * 256 + tid;
            const int row = idx >> 3;
            const int sc = ((idx & 7) * 16) ^ ((row & 7) << 4);
            const int ldsu = (L * 256 + (tid & ~63)) * 8;
            GLOAD_LDS16(Ap + (size_t)(m0 + row) * ldA + k0 + (sc >> 1) + aoff,
                        &As[b][ldsu]);
            GLOAD_LDS16(Bp + (size_t)(n0 + row) * ldB + k0 + (sc >> 1) + boff,
                        &Bs[b][ldsu]);
        }
    };

    STAGE(0, 0);

    for (int t = 0; t < nt; ++t) {
        const int cur = t & 1;
        __builtin_amdgcn_s_barrier();
        asm volatile("" ::: "memory");
        if (t + 1 < nt) {
            STAGE(t + 1, cur ^ 1);
            asm volatile("s_waitcnt vmcnt(8)" ::: "memory");
        } else {
            asm volatile("s_waitcnt vmcnt(0)" ::: "memory");
        }
        __builtin_amdgcn_s_barrier();
        asm volatile("" ::: "memory");

#pragma unroll
        for (int kk = 0; kk < 2; ++kk) {
            const int cb = kk * 64 + (lane >> 4) * 16;
            f16x8 af[4], bv[4];
#pragma unroll
            for (int i = 0; i < 4; ++i) {
                const int r = wr * 64 + i * 16 + (lane & 15);
                af[i] = *(const f16x8*)(&As[cur][r * 64 +
                                                 ((cb ^ ((r & 7) << 4)) >> 1)]);
            }
#pragma unroll
            for (int j = 0; j < 4; ++j) {
                const int r = wc * 64 + j * 16 + (lane & 15);
                bv[j] = *(const f16x8*)(&Bs[cur][r * 64 +
                                                 ((cb ^ ((r & 7) << 4)) >> 1)]);
            }
            __builtin_amdgcn_s_setprio(1);
#pragma unroll
            for (int i = 0; i < 4; ++i)
#pragma unroll
                for (int j = 0; j < 4; ++j)
                    acc[i][j] = __builtin_amdgcn_mfma_f32_16x16x32_f16(
                        af[i], bv[j], acc[i][j], 0, 0, 0);
            __builtin_amdgcn_s_setprio(0);
        }
    }

    const int row0 = m0 + wr * 64 + (lane >> 4) * 4;
    const int col0 = n0 + wc * 64 + (lane & 15);

    if (epi == EPI_F32) {
        float* O = (float*)o0;
#pragma unroll
        for (int i = 0; i < 4; ++i)
#pragma unroll
            for (int j = 0; j < 4; ++j)
#pragma unroll
                for (int q = 0; q < 4; ++q)
                    O[(size_t)(row0 + i * 16 + q) * N + col0 + j * 16] =
                        acc[i][j][q] * scale;
    } else if (epi == EPI_SPLIT16) {
        f16* Hi = (f16*)o0;
        f16* Lo = (f16*)o1;
#pragma unroll
        for (int i = 0; i < 4; ++i)
#pragma unroll
            for (int j = 0; j < 4; ++j)
#pragma unroll
                for (int q = 0; q < 4; ++q) {
                    const float x = acc[i][j][q];
                    const f16 h = (f16)x;
                    const size_t idx = (size_t)(row0 + i * 16 + q) * N + col0 + j * 16;
                    Hi[idx] = h;
                    Lo[idx] = (f16)(x - (float)h);
                }
    } else {  // EPI_TRANS16: out[col][row] over SEQ rows
        f16* OT = (f16*)o0;
#pragma unroll
        for (int i = 0; i < 4; ++i)
#pragma unroll
            for (int j = 0; j < 4; ++j) {
                f16x4 v;
#pragma unroll
                for (int q = 0; q < 4; ++q) v[q] = (f16)acc[i][j][q];
                *(f16x4*)&OT[(size_t)(col0 + j * 16) * SEQ + row0 + i * 16] = v;
            }
    }
}

// ---------------------------------------------------------------------------
// QK~ 256x256 fp16 GEMM + rank-1 epilogue + block-local softmax (round 10).
// ---------------------------------------------------------------------------
template <int NPAIR, int KT>
__global__ __launch_bounds__(512, 2) void qkrank1(
    const f16* __restrict__ A0, const f16* __restrict__ B0,
    const f16* __restrict__ A1, const f16* __restrict__ B1,
    const float* __restrict__ sx, const float* __restrict__ rq,
    const float* __restrict__ rk,
    f16* __restrict__ Pu, float* __restrict__ Mp, float* __restrict__ Lp) {
    constexpr int K = KT * 64;
    constexpr int nt = NPAIR * KT;
    __shared__ __align__(16) f16 As[2][256 * 64];   // 64 KB
    __shared__ __align__(16) f16 Bs[2][256 * 64];   // 64 KB

    const int tid = threadIdx.x;
    const int lane = tid & 63;
    const int wid = tid >> 6;
    const int wr = wid >> 2;
    const int wc = wid & 3;

    const int wg = ((int)blockIdx.x & 7) * 32 + ((int)blockIdx.x >> 3);
    const int m0 = (wg >> 4) * 256;
    const int n0 = (wg & 15) * 256;
    const int bcol = n0 >> 8;

    const f16* APs[2] = {A0, A1};
    const f16* BPs[2] = {B0, B1};

    f32x4 acc[8][4];
#pragma unroll
    for (int i = 0; i < 8; ++i)
#pragma unroll
        for (int j = 0; j < 4; ++j) acc[i][j] = (f32x4){0.f, 0.f, 0.f, 0.f};

    auto STAGE = [&](int t, int b) {
        const f16* Ap = APs[t / KT];
        const f16* Bp = BPs[t / KT];
        const int k0 = (t % KT) * 64;
#pragma unroll
        for (int L = 0; L < 4; ++L) {
            const int idx = L * 512 + tid;
            const int row = idx >> 3;
            const int sc = ((idx & 7) * 16) ^ ((row & 7) << 4);
            const int ldsu = (L * 512 + (tid & ~63)) * 8;
            GLOAD_LDS16(Ap + (size_t)(m0 + row) * K + k0 + (sc >> 1),
                        &As[b][ldsu]);
            GLOAD_LDS16(Bp + (size_t)(n0 + row) * K + k0 + (sc >> 1),
                        &Bs[b][ldsu]);
        }
    };

    STAGE(0, 0);

    for (int t = 0; t < nt; ++t) {
        const int cur = t & 1;
        __builtin_amdgcn_s_barrier();
        asm volatile("" ::: "memory");
        if (t + 1 < nt) {
            STAGE(t + 1, cur ^ 1);
            asm volatile("s_waitcnt vmcnt(8)" ::: "memory");
        } else {
            asm volatile("s_waitcnt vmcnt(0)" ::: "memory");
        }
        __builtin_amdgcn_s_barrier();
        asm volatile("" ::: "memory");

#pragma unroll
        for (int kk = 0; kk < 2; ++kk) {
            const int cb = kk * 64 + (lane >> 4) * 16;
            f16x8 af[8], bv[4];
#pragma unroll
            for (int i = 0; i < 8; ++i) {
                const int r = wr * 128 + i * 16 + (lane & 15);
                af[i] = *(const f16x8*)(&As[cur][r * 64 +
                                                 ((cb ^ ((r & 7) << 4)) >> 1)]);
            }
#pragma unroll
            for (int j = 0; j < 4; ++j) {
                const int r = wc * 64 + j * 16 + (lane & 15);
                bv[j] = *(const f16x8*)(&Bs[cur][r * 64 +
                                                 ((cb ^ ((r & 7) << 4)) >> 1)]);
            }
            __builtin_amdgcn_s_setprio(1);
#pragma unroll
            for (int i = 0; i < 8; ++i)
#pragma unroll
                for (int j = 0; j < 4; ++j)
                    acc[i][j] = __builtin_amdgcn_mfma_f32_16x16x32_f16(
                        af[i], bv[j], acc[i][j], 0, 0, 0);
            __builtin_amdgcn_s_setprio(0);
        }
    }

    // ---- epilogue: rank-1 + scale (in place) ----
    const int g4 = lane >> 4;
    const int l15 = lane & 15;
    const int row0 = m0 + wr * 128 + g4 * 4;   // + i*16 + q
    const int col0 = n0 + wc * 64 + l15;       // + j*16
    float u[4], w4[4];
#pragma unroll
    for (int j = 0; j < 4; ++j) {
        const float sxc = sx[col0 + j * 16];
        u[j] = 256.f * sxc + 0.5f * rk[col0 + j * 16];
        w4[j] = 0.5f * sxc;
    }
#pragma unroll
    for (int i = 0; i < 8; ++i)
#pragma unroll
        for (int q = 0; q < 4; ++q) {
            const int r = row0 + i * 16 + q;
            const float sxr = sx[r];
            const float rqr = rq[r];
#pragma unroll
            for (int j = 0; j < 4; ++j)
                acc[i][j][q] =
                    (acc[i][j][q] + sxr * u[j] + rqr * w4[j]) * 0.03125f;
        }

    // ---- block-local softmax over the 256-col strip ----
    float* partm = (float*)&As[0][0];      // [256][4]
    float* mrow  = partm + 1024;           // [256]
    float* parts = mrow + 256;             // [256][4]
    float red[8][4];
#pragma unroll
    for (int i = 0; i < 8; ++i)
#pragma unroll
        for (int q = 0; q < 4; ++q) {
            float v = acc[i][0][q];
#pragma unroll
            for (int j = 1; j < 4; ++j) v = fmaxf(v, acc[i][j][q]);
            red[i][q] = v;
        }
#pragma unroll
    for (int msk = 1; msk < 16; msk <<= 1)
#pragma unroll
        for (int i = 0; i < 8; ++i)
#pragma unroll
            for (int q = 0; q < 4; ++q)
                red[i][q] = fmaxf(red[i][q], __shfl_xor(red[i][q], msk));
    __syncthreads();
    if (l15 == 0)
#pragma unroll
        for (int i = 0; i < 8; ++i)
#pragma unroll
            for (int q = 0; q < 4; ++q)
                partm[(wr * 128 + i * 16 + g4 * 4 + q) * 4 + wc] = red[i][q];
    __syncthreads();
    if (tid < 256) {
        const float* p = partm + tid * 4;
        mrow[tid] = fmaxf(fmaxf(p[0], p[1]), fmaxf(p[2], p[3]));
    }
    __syncthreads();
#pragma unroll
    for (int i = 0; i < 8; ++i)
#pragma unroll
        for (int q = 0; q < 4; ++q) {
            const float mB = mrow[wr * 128 + i * 16 + g4 * 4 + q];
            float s = 0.f;
#pragma unroll
            for (int j = 0; j < 4; ++j) {
                const float e = __expf(acc[i][j][q] - mB);
                acc[i][j][q] = e;
                s += e;
            }
            red[i][q] = s;
        }
#pragma unroll
    for (int msk = 1; msk < 16; msk <<= 1)
#pragma unroll
        for (int i = 0; i < 8; ++i)
#pragma unroll
            for (int q = 0; q < 4; ++q) red[i][q] += __shfl_xor(red[i][q], msk);
    if (l15 == 0)
#pragma unroll
        for (int i = 0; i < 8; ++i)
#pragma unroll
            for (int q = 0; q < 4; ++q)
                parts[(wr * 128 + i * 16 + g4 * 4 + q) * 4 + wc] = red[i][q];
    __syncthreads();
    if (tid < 256) {
        const float* p = parts + tid * 4;
        Mp[(size_t)(m0 + tid) * 16 + bcol] = mrow[tid];
        Lp[(size_t)(m0 + tid) * 16 + bcol] = p[0] + p[1] + p[2] + p[3];
    }
    // ---- write Pu (f16) ----
#pragma unroll
    for (int i = 0; i < 8; ++i)
#pragma unroll
        for (int q = 0; q < 4; ++q) {
            const size_t r = row0 + i * 16 + q;
#pragma unroll
            for (int j = 0; j < 4; ++j)
                Pu[r * SEQ + col0 + j * 16] = (f16)acc[i][j][q];
        }
}

// ---------------------------------------------------------------------------
// rowfix: per row combine the 16 block-local (m_b, l_b), rescale Pu in place.
// ---------------------------------------------------------------------------
__global__ __launch_bounds__(256) void rowfix(const float* __restrict__ Mp,
                                              const float* __restrict__ Lp,
                                              f16* __restrict__ Pu) {
    __shared__ float mls[32];
    const int tid = threadIdx.x;
    const size_t r = blockIdx.x;
    if (tid < 32)
        mls[tid] = (tid < 16) ? Mp[r * 16 + tid] : Lp[r * 16 + tid - 16];
    __syncthreads();
    float m = -1e30f;
#pragma unroll
    for (int b = 0; b < 16; ++b) m = fmaxf(m, mls[b]);
    float l = 0.f;
#pragma unroll
    for (int b = 0; b < 16; ++b) l += __expf(mls[b] - m) * mls[16 + b];
    const float inv = 1.f / l;

    f16* row = Pu + r * SEQ;
#pragma unroll
    for (int p = 0; p < 2; ++p) {
        const int c0 = p * 2048 + tid * 8;
        const float d = __expf(mls[c0 >> 8] - m) * inv;
        f16x8 v = *(const f16x8*)(row + c0);
#pragma unroll
        for (int e = 0; e < 8; ++e) v[e] = (f16)((float)v[e] * d);
        *(f16x8*)(row + c0) = v;
    }
}

// ---------------------------------------------------------------------------
// addf: O = P0 + P1 (f32), vectorized by 4.
// ---------------------------------------------------------------------------
__global__ __launch_bounds__(256) void addf(const float* __restrict__ a,
                                            const float* __restrict__ b,
                                            float* __restrict__ o) {
    const int i = blockIdx.x * 256 + threadIdx.x;
    const float4 x = ((const float4*)a)[i];
    const float4 y = ((const float4*)b)[i];
    ((float4*)o)[i] = make_float4(x.x + y.x, x.y + y.y, x.z + y.z, x.w + y.w);
}

// ---------------------------------------------------------------------------
extern "C" void kernel_launch(void* const* d_in, const int* in_sizes, int n_in,
                              void* d_out, int out_size, void* d_ws, size_t ws_size,
                              hipStream_t stream) {
    const float* x  = (const float*)d_in[0];
    const float* wq = (const float*)d_in[1];
    const float* wk = (const float*)d_in[2];
    const float* wv = (const float*)d_in[3];
    float* O = (float*)d_out;

    char* ws = (char*)d_ws;
    const size_t MB = 1024 * 1024;
    const size_t KB = 1024;
    f16* Qh = (f16*)(ws + 0 * MB);        // live: proj -> qk
    f16* Ql = (f16*)(ws + 8 * MB);
    f16* Kh = (f16*)(ws + 16 * MB);
    f16* VT = (f16*)(ws + 24 * MB);       // live: vproj -> pv
    float* sx = (float*)(ws + 32 * MB);   // scalars region 32..33 MB
    float* rq = (float*)(ws + 32 * MB + 16 * KB);
    float* rk = (float*)(ws + 32 * MB + 32 * KB);
    float* Mp = (float*)(ws + 32 * MB + 48 * KB);    // [4096][16]
    float* Lp = (float*)(ws + 32 * MB + 304 * KB);   // [4096][16]
    f16* Pu = (f16*)(ws + 40 * MB);       // 32 MB, written by qkrank1
    float* P0 = (float*)(ws + 72 * MB);   // 16 MB PV partial (K half 0)
    float* P1 = (float*)(ws + 88 * MB);   // 16 MB PV partial (K half 1)
    // Dead-before-Pu region (all consumed before qkrank1 writes):
    f16* Xh  = (f16*)(ws + 40 * MB);
    f16* Xl  = (f16*)(ws + 48 * MB);
    f16* Wqh = (f16*)(ws + 56 * MB);
    f16* Wkh = (f16*)(ws + 58 * MB);
    f16* Wvh = (f16*)(ws + 60 * MB);
    f16* Kl  = (f16*)(ws + 64 * MB);      // read only by rowsum_hl

    split16rs<<<4096, 256, 0, stream>>>(x, Xh, Xl, sx);
    wtrans3h<<<dim3(DIM / 32, DIM / 32, 3), 256, 0, stream>>>(
        wq, wk, wv, Wqh, Wkh, Wvh);

    // All three projections in one dispatch (sets: Q, K, V), 2-pass each.
    gemm128s<2, 16><<<dim3(32, 24), 256, 0, stream>>>(
        Xh, Xl, DIM, DIM,
        Wqh, Wqh, Qh, Ql,
        Wkh, Wkh, Kh, Kl,
        Wvh, Wvh, VT, nullptr,
        0, 0,
        EPI_SPLIT16, EPI_SPLIT16, EPI_TRANS16,
        DIM, 1.f);

    rowsum_hl<<<dim3(1024, 2), 256, 0, stream>>>(Qh, Ql, Kh, Kl, rq, rk);

    // Pu = exp(S - m_b) per 256-col strip + (m_b, l_b) partials.
    qkrank1<2, 16><<<256, 512, 0, stream>>>(
        Qh, Kh, Ql, Kh, sx, rq, rk, Pu, Mp, Lp);

    // Normalize: Pu *= exp(m_b - m)/l  ->  P.
    rowfix<<<4096, 256, 0, stream>>>(Mp, Lp, Pu);

    // O = P @ V, split-K x2 for 2 blocks/CU: set0 k<2048 -> P0, set1 -> P1.
    gemm128s<1, 32><<<dim3(32, 16), 256, 0, stream>>>(
        Pu, Pu, SEQ, SEQ,
        VT, VT, P0, nullptr,
        VT, VT, P1, nullptr,
        VT, VT, P1, nullptr,
        2048, 2048,
        EPI_F32, EPI_F32, EPI_F32,
        DIM, 1.f);

    addf<<<4096, 256, 0, stream>>>(P0, P1, O);
}

// Round 12
// 225.191 us; speedup vs baseline: 1.3182x; 1.0111x over previous
//
#include <hip/hip_runtime.h>
#include <math.h>

#define SEQ 4096
#define DIM 1024

typedef _Float16 f16;
typedef _Float16 f16x8 __attribute__((ext_vector_type(8)));
typedef _Float16 f16x4 __attribute__((ext_vector_type(4)));
typedef float f32x4 __attribute__((ext_vector_type(4)));

#define GLOAD_LDS16(g, l)                                              \
    __builtin_amdgcn_global_load_lds(                                  \
        (const __attribute__((address_space(1))) void*)(g),            \
        (__attribute__((address_space(3))) void*)(l), 16, 0, 0)

// ---------------------------------------------------------------------------
// Split f32 -> (hi, lo) fp16 + per-row sum.  One block == one row (DIM=1024).
// ---------------------------------------------------------------------------
__global__ __launch_bounds__(256) void split16rs(const float* __restrict__ in,
                                                 f16* __restrict__ hi,
                                                 f16* __restrict__ lo,
                                                 float* __restrict__ sx) {
    __shared__ float sred[4];
    const int tid = threadIdx.x;
    const int i = blockIdx.x * 256 + tid;
    const float4 v = ((const float4*)in)[i];
    const float vv[4] = {v.x, v.y, v.z, v.w};
    f16x4 h, l;
#pragma unroll
    for (int q = 0; q < 4; ++q) {
        const f16 hq = (f16)vv[q];
        h[q] = hq;
        l[q] = (f16)(vv[q] - (float)hq);
    }
    ((f16x4*)hi)[i] = h;
    ((f16x4*)lo)[i] = l;
    float s = v.x + v.y + v.z + v.w;
#pragma unroll
    for (int m = 32; m >= 1; m >>= 1) s += __shfl_xor(s, m);
    if ((tid & 63) == 0) sred[tid >> 6] = s;
    __syncthreads();
    if (tid == 0) sx[blockIdx.x] = sred[0] + sred[1] + sred[2] + sred[3];
}

// ---------------------------------------------------------------------------
// Transpose-convert weights -> W^T fp16.  z=0: wq-0.5, z=1: wk-0.5, z=2: wv.
// ---------------------------------------------------------------------------
__global__ __launch_bounds__(256) void wtrans3h(
    const float* __restrict__ Wq, const float* __restrict__ Wk,
    const float* __restrict__ Wv,
    f16* __restrict__ QT, f16* __restrict__ KT, f16* __restrict__ VT) {
    __shared__ float tile[32][33];
    const int tid = threadIdx.x;
    const int r0 = blockIdx.x * 32;  // W row (k)
    const int c0 = blockIdx.y * 32;  // W col (n)
    const int z = blockIdx.z;
    const float* W = (z == 0) ? Wq : (z == 1) ? Wk : Wv;
    f16* T = (z == 0) ? QT : (z == 1) ? KT : VT;
    const float off = (z < 2) ? 0.5f : 0.0f;
    {
        const int r = tid >> 3, c = (tid & 7) * 4;
        const float4 v = *(const float4*)&W[(size_t)(r0 + r) * DIM + c0 + c];
        tile[r][c + 0] = v.x;
        tile[r][c + 1] = v.y;
        tile[r][c + 2] = v.z;
        tile[r][c + 3] = v.w;
    }
    __syncthreads();
    {
        const int n = tid >> 3;
        const int k = (tid & 7) * 4;
        f16x4 h;
#pragma unroll
        for (int q = 0; q < 4; ++q) h[q] = (f16)(tile[k + q][n] - off);
        *(f16x4*)&T[(size_t)(c0 + n) * DIM + r0 + k] = h;
    }
}

// ---------------------------------------------------------------------------
// Generalized 128x128 fp16 MFMA GEMM (proven schedule): BK=64, 256 thr,
// double-buffered counted-vmcnt, XOR swizzle, XCD swizzle.  3 sets by by>>3.
// EPI_SPLIT16 additionally: fused per-row sum -> atomicAdd into rs (if set).
// ---------------------------------------------------------------------------
#define EPI_F32 0
#define EPI_SPLIT16 1
#define EPI_TRANS16 2

template <int NPAIR, int KTILES>
__global__ __launch_bounds__(256, 2) void gemm128s(
    const f16* __restrict__ A0, const f16* __restrict__ A1, int ldA, int ldB,
    const f16* __restrict__ B0_0, const f16* __restrict__ B1_0,
    void* o0_0, void* o1_0,
    const f16* __restrict__ B0_1, const f16* __restrict__ B1_1,
    void* o0_1, void* o1_1,
    const f16* __restrict__ B0_2, const f16* __restrict__ B1_2,
    void* o0_2, void* o1_2,
    float* rs0, float* rs1,
    int epi0, int epi1, int epi2,
    int N, float scale) {
    __shared__ __align__(16) f16 As[2][128 * 64];
    __shared__ __align__(16) f16 Bs[2][128 * 64];

    const int tid = threadIdx.x;
    const int lane = tid & 63;
    const int wid = tid >> 6;
    const int wr = wid >> 1, wc = wid & 1;

    const int total = (int)(gridDim.y << 5);
    int lid = (int)blockIdx.y * 32 + (int)blockIdx.x;
    lid = (lid & 7) * (total >> 3) + (lid >> 3);
    const int bx = lid & 31;
    int by = lid >> 5;

    const int set = by >> 3;
    by &= 7;

    const f16 *B0, *B1;
    void *o0, *o1;
    int epi;
    float* rs;
    if (set == 0)      { B0 = B0_0; B1 = B1_0; o0 = o0_0; o1 = o1_0; epi = epi0; rs = rs0; }
    else if (set == 1) { B0 = B0_1; B1 = B1_1; o0 = o0_1; o1 = o1_1; epi = epi1; rs = rs1; }
    else               { B0 = B0_2; B1 = B1_2; o0 = o0_2; o1 = o1_2; epi = epi2; rs = nullptr; }

    const int m0 = bx * 128;
    const int n0 = by * 128;

    const f16* APs[2] = {A0, A1};
    const f16* BPs[2] = {B0, B1};
    const int nt = NPAIR * KTILES;

    f32x4 acc[4][4];
#pragma unroll
    for (int i = 0; i < 4; ++i)
#pragma unroll
        for (int j = 0; j < 4; ++j) acc[i][j] = (f32x4){0.f, 0.f, 0.f, 0.f};

    auto STAGE = [&](int t, int b) {
        const int pass = t / KTILES;
        const int k0 = (t % KTILES) * 64;
        const f16* Ap = APs[pass];
        const f16* Bp = BPs[pass];
#pragma unroll
        for (int L = 0; L < 4; ++L) {
            const int idx = L * 256 + tid;
            const int row = idx >> 3;
            const int sc = ((idx & 7) * 16) ^ ((row & 7) << 4);
            const int ldsu = (L * 256 + (tid & ~63)) * 8;
            GLOAD_LDS16(Ap + (size_t)(m0 + row) * ldA + k0 + (sc >> 1),
                        &As[b][ldsu]);
            GLOAD_LDS16(Bp + (size_t)(n0 + row) * ldB + k0 + (sc >> 1),
                        &Bs[b][ldsu]);
        }
    };

    STAGE(0, 0);

    for (int t = 0; t < nt; ++t) {
        const int cur = t & 1;
        __builtin_amdgcn_s_barrier();
        asm volatile("" ::: "memory");
        if (t + 1 < nt) {
            STAGE(t + 1, cur ^ 1);
            asm volatile("s_waitcnt vmcnt(8)" ::: "memory");
        } else {
            asm volatile("s_waitcnt vmcnt(0)" ::: "memory");
        }
        __builtin_amdgcn_s_barrier();
        asm volatile("" ::: "memory");

#pragma unroll
        for (int kk = 0; kk < 2; ++kk) {
            const int cb = kk * 64 + (lane >> 4) * 16;
            f16x8 af[4], bv[4];
#pragma unroll
            for (int i = 0; i < 4; ++i) {
                const int r = wr * 64 + i * 16 + (lane & 15);
                af[i] = *(const f16x8*)(&As[cur][r * 64 +
                                                 ((cb ^ ((r & 7) << 4)) >> 1)]);
            }
#pragma unroll
            for (int j = 0; j < 4; ++j) {
                const int r = wc * 64 + j * 16 + (lane & 15);
                bv[j] = *(const f16x8*)(&Bs[cur][r * 64 +
                                                 ((cb ^ ((r & 7) << 4)) >> 1)]);
            }
            __builtin_amdgcn_s_setprio(1);
#pragma unroll
            for (int i = 0; i < 4; ++i)
#pragma unroll
                for (int j = 0; j < 4; ++j)
                    acc[i][j] = __builtin_amdgcn_mfma_f32_16x16x32_f16(
                        af[i], bv[j], acc[i][j], 0, 0, 0);
            __builtin_amdgcn_s_setprio(0);
        }
    }

    const int row0 = m0 + wr * 64 + (lane >> 4) * 4;
    const int col0 = n0 + wc * 64 + (lane & 15);

    if (epi == EPI_F32) {
        float* O = (float*)o0;
#pragma unroll
        for (int i = 0; i < 4; ++i)
#pragma unroll
            for (int j = 0; j < 4; ++j)
#pragma unroll
                for (int q = 0; q < 4; ++q)
                    O[(size_t)(row0 + i * 16 + q) * N + col0 + j * 16] =
                        acc[i][j][q] * scale;
    } else if (epi == EPI_SPLIT16) {
        f16* Hi = (f16*)o0;
        f16* Lo = (f16*)o1;
#pragma unroll
        for (int i = 0; i < 4; ++i)
#pragma unroll
            for (int j = 0; j < 4; ++j)
#pragma unroll
                for (int q = 0; q < 4; ++q) {
                    const float x = acc[i][j][q];
                    const f16 h = (f16)x;
                    const size_t idx = (size_t)(row0 + i * 16 + q) * N + col0 + j * 16;
                    Hi[idx] = h;
                    if (Lo) Lo[idx] = (f16)(x - (float)h);
                }
        // Fused row-sum: rsum over this thread's 4 cols, reduce over the 16
        // lanes sharing rows (l15 group), one atomicAdd per row per wave.
        if (rs) {
#pragma unroll
            for (int i = 0; i < 4; ++i)
#pragma unroll
                for (int q = 0; q < 4; ++q) {
                    float rsum = acc[i][0][q] + acc[i][1][q] +
                                 acc[i][2][q] + acc[i][3][q];
#pragma unroll
                    for (int msk = 1; msk < 16; msk <<= 1)
                        rsum += __shfl_xor(rsum, msk);
                    if ((lane & 15) == 0)
                        atomicAdd(&rs[row0 + i * 16 + q], rsum);
                }
        }
    } else {  // EPI_TRANS16: out[col][row] over SEQ rows
        f16* OT = (f16*)o0;
#pragma unroll
        for (int i = 0; i < 4; ++i)
#pragma unroll
            for (int j = 0; j < 4; ++j) {
                f16x4 v;
#pragma unroll
                for (int q = 0; q < 4; ++q) v[q] = (f16)acc[i][j][q];
                *(f16x4*)&OT[(size_t)(col0 + j * 16) * SEQ + row0 + i * 16] = v;
            }
    }
}

// ---------------------------------------------------------------------------
// QK~ 256x256 fp16 GEMM + rank-1 epilogue + block-local softmax (round 10).
// ---------------------------------------------------------------------------
template <int NPAIR, int KT>
__global__ __launch_bounds__(512, 2) void qkrank1(
    const f16* __restrict__ A0, const f16* __restrict__ B0,
    const f16* __restrict__ A1, const f16* __restrict__ B1,
    const float* __restrict__ sx, const float* __restrict__ rq,
    const float* __restrict__ rk,
    f16* __restrict__ Pu, float* __restrict__ Mp, float* __restrict__ Lp) {
    constexpr int K = KT * 64;
    constexpr int nt = NPAIR * KT;
    __shared__ __align__(16) f16 As[2][256 * 64];   // 64 KB
    __shared__ __align__(16) f16 Bs[2][256 * 64];   // 64 KB

    const int tid = threadIdx.x;
    const int lane = tid & 63;
    const int wid = tid >> 6;
    const int wr = wid >> 2;
    const int wc = wid & 3;

    const int wg = ((int)blockIdx.x & 7) * 32 + ((int)blockIdx.x >> 3);
    const int m0 = (wg >> 4) * 256;
    const int n0 = (wg & 15) * 256;
    const int bcol = n0 >> 8;

    const f16* APs[2] = {A0, A1};
    const f16* BPs[2] = {B0, B1};

    f32x4 acc[8][4];
#pragma unroll
    for (int i = 0; i < 8; ++i)
#pragma unroll
        for (int j = 0; j < 4; ++j) acc[i][j] = (f32x4){0.f, 0.f, 0.f, 0.f};

    auto STAGE = [&](int t, int b) {
        const f16* Ap = APs[t / KT];
        const f16* Bp = BPs[t / KT];
        const int k0 = (t % KT) * 64;
#pragma unroll
        for (int L = 0; L < 4; ++L) {
            const int idx = L * 512 + tid;
            const int row = idx >> 3;
            const int sc = ((idx & 7) * 16) ^ ((row & 7) << 4);
            const int ldsu = (L * 512 + (tid & ~63)) * 8;
            GLOAD_LDS16(Ap + (size_t)(m0 + row) * K + k0 + (sc >> 1),
                        &As[b][ldsu]);
            GLOAD_LDS16(Bp + (size_t)(n0 + row) * K + k0 + (sc >> 1),
                        &Bs[b][ldsu]);
        }
    };

    STAGE(0, 0);

    for (int t = 0; t < nt; ++t) {
        const int cur = t & 1;
        __builtin_amdgcn_s_barrier();
        asm volatile("" ::: "memory");
        if (t + 1 < nt) {
            STAGE(t + 1, cur ^ 1);
            asm volatile("s_waitcnt vmcnt(8)" ::: "memory");
        } else {
            asm volatile("s_waitcnt vmcnt(0)" ::: "memory");
        }
        __builtin_amdgcn_s_barrier();
        asm volatile("" ::: "memory");

#pragma unroll
        for (int kk = 0; kk < 2; ++kk) {
            const int cb = kk * 64 + (lane >> 4) * 16;
            f16x8 af[8], bv[4];
#pragma unroll
            for (int i = 0; i < 8; ++i) {
                const int r = wr * 128 + i * 16 + (lane & 15);
                af[i] = *(const f16x8*)(&As[cur][r * 64 +
                                                 ((cb ^ ((r & 7) << 4)) >> 1)]);
            }
#pragma unroll
            for (int j = 0; j < 4; ++j) {
                const int r = wc * 64 + j * 16 + (lane & 15);
                bv[j] = *(const f16x8*)(&Bs[cur][r * 64 +
                                                 ((cb ^ ((r & 7) << 4)) >> 1)]);
            }
            __builtin_amdgcn_s_setprio(1);
#pragma unroll
            for (int i = 0; i < 8; ++i)
#pragma unroll
                for (int j = 0; j < 4; ++j)
                    acc[i][j] = __builtin_amdgcn_mfma_f32_16x16x32_f16(
                        af[i], bv[j], acc[i][j], 0, 0, 0);
            __builtin_amdgcn_s_setprio(0);
        }
    }

    // ---- epilogue: rank-1 + scale (in place) ----
    const int g4 = lane >> 4;
    const int l15 = lane & 15;
    const int row0 = m0 + wr * 128 + g4 * 4;   // + i*16 + q
    const int col0 = n0 + wc * 64 + l15;       // + j*16
    float u[4], w4[4];
#pragma unroll
    for (int j = 0; j < 4; ++j) {
        const float sxc = sx[col0 + j * 16];
        u[j] = 256.f * sxc + 0.5f * rk[col0 + j * 16];
        w4[j] = 0.5f * sxc;
    }
#pragma unroll
    for (int i = 0; i < 8; ++i)
#pragma unroll
        for (int q = 0; q < 4; ++q) {
            const int r = row0 + i * 16 + q;
            const float sxr = sx[r];
            const float rqr = rq[r];
#pragma unroll
            for (int j = 0; j < 4; ++j)
                acc[i][j][q] =
                    (acc[i][j][q] + sxr * u[j] + rqr * w4[j]) * 0.03125f;
        }

    // ---- block-local softmax over the 256-col strip ----
    float* partm = (float*)&As[0][0];      // [256][4]
    float* mrow  = partm + 1024;           // [256]
    float* parts = mrow + 256;             // [256][4]
    float red[8][4];
#pragma unroll
    for (int i = 0; i < 8; ++i)
#pragma unroll
        for (int q = 0; q < 4; ++q) {
            float v = acc[i][0][q];
#pragma unroll
            for (int j = 1; j < 4; ++j) v = fmaxf(v, acc[i][j][q]);
            red[i][q] = v;
        }
#pragma unroll
    for (int msk = 1; msk < 16; msk <<= 1)
#pragma unroll
        for (int i = 0; i < 8; ++i)
#pragma unroll
            for (int q = 0; q < 4; ++q)
                red[i][q] = fmaxf(red[i][q], __shfl_xor(red[i][q], msk));
    __syncthreads();
    if (l15 == 0)
#pragma unroll
        for (int i = 0; i < 8; ++i)
#pragma unroll
            for (int q = 0; q < 4; ++q)
                partm[(wr * 128 + i * 16 + g4 * 4 + q) * 4 + wc] = red[i][q];
    __syncthreads();
    if (tid < 256) {
        const float* p = partm + tid * 4;
        mrow[tid] = fmaxf(fmaxf(p[0], p[1]), fmaxf(p[2], p[3]));
    }
    __syncthreads();
#pragma unroll
    for (int i = 0; i < 8; ++i)
#pragma unroll
        for (int q = 0; q < 4; ++q) {
            const float mB = mrow[wr * 128 + i * 16 + g4 * 4 + q];
            float s = 0.f;
#pragma unroll
            for (int j = 0; j < 4; ++j) {
                const float e = __expf(acc[i][j][q] - mB);
                acc[i][j][q] = e;
                s += e;
            }
            red[i][q] = s;
        }
#pragma unroll
    for (int msk = 1; msk < 16; msk <<= 1)
#pragma unroll
        for (int i = 0; i < 8; ++i)
#pragma unroll
            for (int q = 0; q < 4; ++q) red[i][q] += __shfl_xor(red[i][q], msk);
    if (l15 == 0)
#pragma unroll
        for (int i = 0; i < 8; ++i)
#pragma unroll
            for (int q = 0; q < 4; ++q)
                parts[(wr * 128 + i * 16 + g4 * 4 + q) * 4 + wc] = red[i][q];
    __syncthreads();
    if (tid < 256) {
        const float* p = parts + tid * 4;
        Mp[(size_t)(m0 + tid) * 16 + bcol] = mrow[tid];
        Lp[(size_t)(m0 + tid) * 16 + bcol] = p[0] + p[1] + p[2] + p[3];
    }
    // ---- write Pu (f16, unnormalized exp) ----
#pragma unroll
    for (int i = 0; i < 8; ++i)
#pragma unroll
        for (int q = 0; q < 4; ++q) {
            const size_t r = row0 + i * 16 + q;
#pragma unroll
            for (int j = 0; j < 4; ++j)
                Pu[r * SEQ + col0 + j * 16] = (f16)acc[i][j][q];
        }
}

// ---------------------------------------------------------------------------
// mkD: D[r][b] = exp(m_b - m) / l  (one thread per row).
// ---------------------------------------------------------------------------
__global__ __launch_bounds__(256) void mkD(const float* __restrict__ Mp,
                                           const float* __restrict__ Lp,
                                           float* __restrict__ D) {
    const size_t r = blockIdx.x * 256 + threadIdx.x;
    float mv[16], lv[16];
#pragma unroll
    for (int b = 0; b < 16; ++b) mv[b] = Mp[r * 16 + b];
#pragma unroll
    for (int b = 0; b < 16; ++b) lv[b] = Lp[r * 16 + b];
    float m = mv[0];
#pragma unroll
    for (int b = 1; b < 16; ++b) m = fmaxf(m, mv[b]);
    float l = 0.f;
#pragma unroll
    for (int b = 0; b < 16; ++b) l += __expf(mv[b] - m) * lv[b];
    const float inv = 1.f / l;
#pragma unroll
    for (int b = 0; b < 16; ++b) D[r * 16 + b] = __expf(mv[b] - m) * inv;
}

// ---------------------------------------------------------------------------
// PV with folded normalization: O_half = sum_strips D[r][strip] * (Pu @ VT).
// Proven 128x128 schedule; strip (256 k) = 4 BK-tiles; at each strip end
// acc2 += D*acc, acc = 0.  Split-K x2 via sets (by>>3) -> P0 / P1.
// ---------------------------------------------------------------------------
template <int KTILES>   // tiles per K-half (32)
__global__ __launch_bounds__(256, 2) void pvstrip(
    const f16* __restrict__ Pu, const f16* __restrict__ VT,
    const float* __restrict__ D,
    float* __restrict__ P0, float* __restrict__ P1) {
    __shared__ __align__(16) f16 As[2][128 * 64];
    __shared__ __align__(16) f16 Bs[2][128 * 64];

    const int tid = threadIdx.x;
    const int lane = tid & 63;
    const int wid = tid >> 6;
    const int wr = wid >> 1, wc = wid & 1;

    const int total = (int)(gridDim.y << 5);
    int lid = (int)blockIdx.y * 32 + (int)blockIdx.x;
    lid = (lid & 7) * (total >> 3) + (lid >> 3);
    const int bx = lid & 31;
    int by = lid >> 5;
    const int set = by >> 3;
    by &= 7;
    float* Out = set ? P1 : P0;
    const int koff = set * 2048;           // element offset along K
    const int strip0 = set * 8;

    const int m0 = bx * 128;
    const int n0 = by * 128;
    const int row0 = m0 + wr * 64 + (lane >> 4) * 4;
    const int col0 = n0 + wc * 64 + (lane & 15);

    f32x4 acc[4][4], acc2[4][4];
#pragma unroll
    for (int i = 0; i < 4; ++i)
#pragma unroll
        for (int j = 0; j < 4; ++j) {
            acc[i][j] = (f32x4){0.f, 0.f, 0.f, 0.f};
            acc2[i][j] = (f32x4){0.f, 0.f, 0.f, 0.f};
        }

    auto STAGE = [&](int t, int b) {
        const int k0 = t * 64 + koff;
#pragma unroll
        for (int L = 0; L < 4; ++L) {
            const int idx = L * 256 + tid;
            const int row = idx >> 3;
            const int sc = ((idx & 7) * 16) ^ ((row & 7) << 4);
            const int ldsu = (L * 256 + (tid & ~63)) * 8;
            GLOAD_LDS16(Pu + (size_t)(m0 + row) * SEQ + k0 + (sc >> 1),
                        &As[b][ldsu]);
            GLOAD_LDS16(VT + (size_t)(n0 + row) * SEQ + k0 + (sc >> 1),
                        &Bs[b][ldsu]);
        }
    };

    STAGE(0, 0);

    for (int t = 0; t < KTILES; ++t) {
        const int cur = t & 1;
        __builtin_amdgcn_s_barrier();
        asm volatile("" ::: "memory");
        if (t + 1 < KTILES) {
            STAGE(t + 1, cur ^ 1);
            asm volatile("s_waitcnt vmcnt(8)" ::: "memory");
        } else {
            asm volatile("s_waitcnt vmcnt(0)" ::: "memory");
        }
        __builtin_amdgcn_s_barrier();
        asm volatile("" ::: "memory");

#pragma unroll
        for (int kk = 0; kk < 2; ++kk) {
            const int cb = kk * 64 + (lane >> 4) * 16;
            f16x8 af[4], bv[4];
#pragma unroll
            for (int i = 0; i < 4; ++i) {
                const int r = wr * 64 + i * 16 + (lane & 15);
                af[i] = *(const f16x8*)(&As[cur][r * 64 +
                                                 ((cb ^ ((r & 7) << 4)) >> 1)]);
            }
#pragma unroll
            for (int j = 0; j < 4; ++j) {
                const int r = wc * 64 + j * 16 + (lane & 15);
                bv[j] = *(const f16x8*)(&Bs[cur][r * 64 +
                                                 ((cb ^ ((r & 7) << 4)) >> 1)]);
            }
            __builtin_amdgcn_s_setprio(1);
#pragma unroll
            for (int i = 0; i < 4; ++i)
#pragma unroll
                for (int j = 0; j < 4; ++j)
                    acc[i][j] = __builtin_amdgcn_mfma_f32_16x16x32_f16(
                        af[i], bv[j], acc[i][j], 0, 0, 0);
            __builtin_amdgcn_s_setprio(0);
        }

        if ((t & 3) == 3) {   // strip boundary: fold D and reset partial
            const int strip = strip0 + (t >> 2);
#pragma unroll
            for (int i = 0; i < 4; ++i)
#pragma unroll
                for (int q = 0; q < 4; ++q) {
                    const float dv = D[(size_t)(row0 + i * 16 + q) * 16 + strip];
#pragma unroll
                    for (int j = 0; j < 4; ++j) {
                        acc2[i][j][q] += dv * acc[i][j][q];
                        acc[i][j][q] = 0.f;
                    }
                }
        }
    }

#pragma unroll
    for (int i = 0; i < 4; ++i)
#pragma unroll
        for (int j = 0; j < 4; ++j)
#pragma unroll
            for (int q = 0; q < 4; ++q)
                Out[(size_t)(row0 + i * 16 + q) * DIM + col0 + j * 16] =
                    acc2[i][j][q];
}

// ---------------------------------------------------------------------------
// addf: O = P0 + P1 (f32), vectorized by 4.
// ---------------------------------------------------------------------------
__global__ __launch_bounds__(256) void addf(const float* __restrict__ a,
                                            const float* __restrict__ b,
                                            float* __restrict__ o) {
    const int i = blockIdx.x * 256 + threadIdx.x;
    const float4 x = ((const float4*)a)[i];
    const float4 y = ((const float4*)b)[i];
    ((float4*)o)[i] = make_float4(x.x + y.x, x.y + y.y, x.z + y.z, x.w + y.w);
}

// ---------------------------------------------------------------------------
extern "C" void kernel_launch(void* const* d_in, const int* in_sizes, int n_in,
                              void* d_out, int out_size, void* d_ws, size_t ws_size,
                              hipStream_t stream) {
    const float* x  = (const float*)d_in[0];
    const float* wq = (const float*)d_in[1];
    const float* wk = (const float*)d_in[2];
    const float* wv = (const float*)d_in[3];
    float* O = (float*)d_out;

    char* ws = (char*)d_ws;
    const size_t MB = 1024 * 1024;
    const size_t KB = 1024;
    f16* Qh = (f16*)(ws + 0 * MB);        // live: proj -> qk
    f16* Ql = (f16*)(ws + 8 * MB);
    f16* Kh = (f16*)(ws + 16 * MB);
    f16* VT = (f16*)(ws + 24 * MB);       // live: vproj -> pv
    float* sx = (float*)(ws + 32 * MB);
    float* rq = (float*)(ws + 32 * MB + 16 * KB);
    float* rk = (float*)(ws + 32 * MB + 32 * KB);
    float* Mp = (float*)(ws + 32 * MB + 48 * KB);    // [4096][16]
    float* Lp = (float*)(ws + 32 * MB + 304 * KB);   // [4096][16]
    float* D  = (float*)(ws + 33 * MB);              // [4096][16]
    f16* Pu = (f16*)(ws + 40 * MB);       // 32 MB, written by qkrank1
    float* P0 = (float*)(ws + 72 * MB);   // 16 MB PV partial (K half 0)
    float* P1 = (float*)(ws + 88 * MB);   // 16 MB PV partial (K half 1)
    // Dead-before-Pu region (all consumed before qkrank1 writes):
    f16* Xh  = (f16*)(ws + 40 * MB);
    f16* Xl  = (f16*)(ws + 48 * MB);
    f16* Wqh = (f16*)(ws + 56 * MB);
    f16* Wkh = (f16*)(ws + 58 * MB);
    f16* Wvh = (f16*)(ws + 60 * MB);

    split16rs<<<4096, 256, 0, stream>>>(x, Xh, Xl, sx);
    wtrans3h<<<dim3(DIM / 32, DIM / 32, 3), 256, 0, stream>>>(
        wq, wk, wv, Wqh, Wkh, Wvh);

    // Zero rq/rk for the fused atomic row-sums.
    hipMemsetAsync(rq, 0, 32 * KB, stream);

    // All three projections in one dispatch (sets: Q, K, V), 2-pass each;
    // Q/K row-sums fused via atomics; K's lo plane not materialized.
    gemm128s<2, 16><<<dim3(32, 24), 256, 0, stream>>>(
        Xh, Xl, DIM, DIM,
        Wqh, Wqh, Qh, Ql,
        Wkh, Wkh, Kh, nullptr,
        Wvh, Wvh, VT, nullptr,
        rq, rk,
        EPI_SPLIT16, EPI_SPLIT16, EPI_TRANS16,
        DIM, 1.f);

    // Pu = exp(S - m_b) per 256-col strip + (m_b, l_b) partials.
    qkrank1<2, 16><<<256, 512, 0, stream>>>(
        Qh, Kh, Ql, Kh, sx, rq, rk, Pu, Mp, Lp);

    // D[r][b] = exp(m_b - m)/l.
    mkD<<<16, 256, 0, stream>>>(Mp, Lp, D);

    // O_half = sum_strips D * (Pu @ V), split-K x2.
    pvstrip<32><<<dim3(32, 16), 256, 0, stream>>>(Pu, VT, D, P0, P1);

    addf<<<4096, 256, 0, stream>>>(P0, P1, O);
}